// Round 6
// baseline (318.965 us; speedup 1.0000x reference)
//
#include <hip/hip_runtime.h>
#include <hip/hip_bf16.h>

// Problem constants
#define Bn 16
#define Cc 512
#define Ss 1024           // H*W tokens per batch
#define HEADS 8
#define DHEAD 64
#define GROUPS 32
#define CPG 16
#define EPSv 1e-5f
#define Mtok (Bn*Ss)      // 16384 token rows
#define QKVS 1536         // (legacy) fused qkv row stride
#define QKS 1024          // Q+K row stride (V split out transposed)
#define PROW 34           // padded image row (32 + halo)
#define PIMG (PROW*PROW)  // 1156 padded tokens per batch

typedef __hip_bfloat16 bf16;
typedef __attribute__((ext_vector_type(8))) short short8;   // MFMA A/B frag (8 bf16)
typedef __attribute__((ext_vector_type(4))) float f32x4;    // MFMA C/D frag

union U4 { uint4 u; bf16 h[8]; };
union B4 { ushort4 u; bf16 h[4]; };

// async global->LDS, 16 B/lane; LDS dest = wave-uniform base + lane*16
__device__ __forceinline__ void stage16(const bf16* g, bf16* l) {
    __builtin_amdgcn_global_load_lds((const __attribute__((address_space(1))) void*)g,
                                     (__attribute__((address_space(3))) void*)l,
                                     16, 0, 0);
}

// pack two f32 -> one dword of 2 bf16 (lo=a, hi=b)
__device__ __forceinline__ unsigned int pkbf(float a, float b) {
    union { __hip_bfloat16 h; unsigned short u; } ua, ub;
    ua.h = __float2bfloat16(a); ub.h = __float2bfloat16(b);
    return ((unsigned int)ub.u << 16) | ua.u;
}

// ---- T2 pair-row XOR swizzle (128-B lines of 8 x 16-B chunks) ----
// logical (row r, chunk c) stored at line=r>>1, pos=((r&1)*4+c)^(line&7)
__device__ __forceinline__ void swz_decode(int F, int& r, int& c) {
    int line = F >> 3, pos = F & 7;
    int u = pos ^ (line & 7);
    r = (line << 1) | (u >> 2);
    c = u & 3;
}
// read offset in bf16 elems for logical (r, chunk q)
__device__ __forceinline__ int swz_off(int r, int q) {
    return (r >> 1) * 64 + (((((r & 1) << 2) + q) ^ ((r >> 1) & 7)) << 3);
}

// ---------------------------------------------------------------------------
// 0) Weight transpose+convert: src f32 [512][512] (k-major) -> dst bf16 [n][k]
// ---------------------------------------------------------------------------
__global__ __launch_bounds__(256) void wtrans(const float* __restrict__ src,
                                              bf16* __restrict__ dst) {
    size_t off = (size_t)blockIdx.y * 262144;
    int t = blockIdx.x * 256 + threadIdx.x;     // 0..32767
    int n = t & 511, k8 = (t >> 9) * 8;
    const float* s = src + off + (size_t)k8 * 512 + n;
    U4 o;
#pragma unroll
    for (int j = 0; j < 8; j++) o.h[j] = __float2bfloat16(s[(size_t)j * 512]);
    *(uint4*)(dst + off + (size_t)n * 512 + k8) = o.u;
}

// ---------------------------------------------------------------------------
// 1) GroupNorm stats
// ---------------------------------------------------------------------------
__global__ __launch_bounds__(256) void gn_stats(const float* __restrict__ x,
                                                float* __restrict__ stats) {
    int bg = blockIdx.x;
    int b = bg >> 5, g = bg & 31;
    int tid = threadIdx.x;
    const size_t base = (size_t)b * Ss * Cc + g * CPG;
    float sum = 0.f, sq = 0.f;
    for (int i = tid; i < 4096; i += 256) {
        int s = i >> 2, c4 = (i & 3) * 4;
        float4 t = *(const float4*)(x + base + (size_t)s * Cc + c4);
        sum += t.x + t.y + t.z + t.w;
        sq  += t.x * t.x + t.y * t.y + t.z * t.z + t.w * t.w;
    }
    __shared__ float s1[4], s2[4];
#pragma unroll
    for (int off = 32; off > 0; off >>= 1) {
        sum += __shfl_down(sum, off);
        sq  += __shfl_down(sq,  off);
    }
    if ((tid & 63) == 0) { s1[tid >> 6] = sum; s2[tid >> 6] = sq; }
    __syncthreads();
    if (tid == 0) {
        float S = s1[0] + s1[1] + s1[2] + s1[3];
        float Q = s2[0] + s2[1] + s2[2] + s2[3];
        float mean = S * (1.f / 16384.f);
        float var  = Q * (1.f / 16384.f) - mean * mean;
        stats[bg * 2 + 0] = mean;
        stats[bg * 2 + 1] = rsqrtf(var + EPSv);
    }
}

// ---------------------------------------------------------------------------
// 2) GroupNorm apply (f32 in, bf16 out)
// ---------------------------------------------------------------------------
__global__ __launch_bounds__(256) void gn_apply(const float* __restrict__ x,
                                                const float* __restrict__ stats,
                                                const float* __restrict__ gamma,
                                                const float* __restrict__ beta,
                                                bf16* __restrict__ xn) {
    size_t i = (size_t)blockIdx.x * 256 + threadIdx.x;
    size_t e = i * 4;
    int c0 = (int)(e & (Cc - 1));
    int token = (int)(e >> 9);
    int b = token >> 10;
    int g = c0 >> 4;
    float mean = stats[(b * 32 + g) * 2 + 0];
    float rstd = stats[(b * 32 + g) * 2 + 1];
    float4 t  = *(const float4*)(x + e);
    float4 gm = *(const float4*)(gamma + c0);
    float4 bt = *(const float4*)(beta + c0);
    B4 o;
    o.h[0] = __float2bfloat16((t.x - mean) * rstd * gm.x + bt.x);
    o.h[1] = __float2bfloat16((t.y - mean) * rstd * gm.y + bt.y);
    o.h[2] = __float2bfloat16((t.z - mean) * rstd * gm.z + bt.z);
    o.h[3] = __float2bfloat16((t.w - mean) * rstd * gm.w + bt.w);
    *(ushort4*)(xn + e) = o.u;
}

// ---------------------------------------------------------------------------
// 2b) Zero the padded-activation border (132 border tokens x 512 ch x 16 b)
// ---------------------------------------------------------------------------
__global__ __launch_bounds__(256) void zero_pad(bf16* __restrict__ Pad) {
    int idx = blockIdx.x * 256 + threadIdx.x;     // exactly 16*132*64
    int b = idx / (132 * 64);
    int rem = idx - b * 132 * 64;
    int t = rem >> 6, seg = rem & 63;
    int r, c;
    if (t < 34)      { r = 0;  c = t; }
    else if (t < 68) { r = 33; c = t - 34; }
    else { int u = t - 68; r = 1 + (u >> 1); c = (u & 1) * 33; }
    uint4 z = {0u, 0u, 0u, 0u};
    *(uint4*)(Pad + ((size_t)b * PIMG + r * PROW + c) * Cc + seg * 8) = z;
}

// ---------------------------------------------------------------------------
// 3) Fused QKV GEMM, m97-style. Q,K -> QK buffer (row stride 1024);
//    V -> TRANSPOSED buffer vT[h][d][b*1024+tok] (packed 8B stores along tok).
// ---------------------------------------------------------------------------
__global__ __launch_bounds__(256) void gemm_qkv(const bf16* __restrict__ A,
                                                const bf16* __restrict__ Wt,
                                                bf16* __restrict__ C,
                                                bf16* __restrict__ vT) {
    __shared__ __align__(16) bf16 As[128][32];
    __shared__ __align__(16) bf16 Bs[128][32];
    int tid = threadIdx.x;
    int wave = tid >> 6, lane = tid & 63;
    int l15 = lane & 15, quad = lane >> 4;
    int wm = wave >> 1, wn = wave & 1;
    int m0 = blockIdx.y * 128, n0 = blockIdx.x * 128;
    int lr = lane >> 2, kseg = (lane & 3) * 8;
    int ar0 = wave * 32 + lr;                      // tile row staged by this lane

    const bf16* ga = A  + (size_t)(m0 + ar0) * Cc + kseg;
    const bf16* gb = Wt + (size_t)(n0 + ar0) * Cc + kseg;
    bf16* la0 = &As[wave * 32][0];
    bf16* la1 = &As[wave * 32 + 16][0];
    bf16* lb0 = &Bs[wave * 32][0];
    bf16* lb1 = &Bs[wave * 32 + 16][0];

    f32x4 acc[4][4] = {};
    for (int k0 = 0; k0 < 512; k0 += 32) {
        __syncthreads();
        stage16(ga + k0,                  la0);
        stage16(ga + k0 + (size_t)16 * Cc, la1);
        stage16(gb + k0,                  lb0);
        stage16(gb + k0 + (size_t)16 * Cc, lb1);
        __syncthreads();
        short8 af[4], bfv[4];
#pragma unroll
        for (int mt = 0; mt < 4; mt++) af[mt]  = *(const short8*)&As[wm * 64 + mt * 16 + l15][quad * 8];
#pragma unroll
        for (int nt = 0; nt < 4; nt++) bfv[nt] = *(const short8*)&Bs[wn * 64 + nt * 16 + l15][quad * 8];
#pragma unroll
        for (int mt = 0; mt < 4; mt++)
#pragma unroll
            for (int nt = 0; nt < 4; nt++)
                acc[mt][nt] = __builtin_amdgcn_mfma_f32_16x16x32_bf16(af[mt], bfv[nt], acc[mt][nt], 0, 0, 0);
    }

    if (n0 < 1024) {
        // Q/K: normal store, row stride QKS
#pragma unroll
        for (int mt = 0; mt < 4; mt++)
#pragma unroll
            for (int r = 0; r < 4; r++) {
                size_t row = (size_t)(m0 + wm * 64 + mt * 16 + quad * 4 + r) * QKS + n0 + wn * 64 + l15;
#pragma unroll
                for (int nt = 0; nt < 4; nt++)
                    C[row + nt * 16] = __float2bfloat16(acc[mt][nt][r]);
            }
    } else {
        // V: transposed store vT[(h*64+d)][b*1024 + tok], 8B packed along tok
        int hh = ((n0 - 1024) >> 6) + wn;          // head
        int bq = m0 >> 10;
        int tok0 = (m0 & 1023) + wm * 64;
#pragma unroll
        for (int nt = 0; nt < 4; nt++) {
            int d = nt * 16 + l15;
            bf16* drow = vT + (size_t)(hh * 64 + d) * 16384 + bq * 1024 + tok0;
#pragma unroll
            for (int mt = 0; mt < 4; mt++) {
                B4 o;
#pragma unroll
                for (int r = 0; r < 4; r++) o.h[r] = __float2bfloat16(acc[mt][nt][r]);
                *(ushort4*)(drow + mt * 16 + quad * 4) = o.u;
            }
        }
    }
}

// ---------------------------------------------------------------------------
// 4) Flash-style MFMA attention, KVBLK=64, 2-phase counted-vmcnt dbuf,
//    Q-BLOCKED: each wave owns 32 q-rows (2 sub-blocks) so each K/V LDS
//    fragment read is reused for 2 q-blocks — K/V LDS traffic per unit work
//    halved (was the 4x cross-wave duplication bottleneck). Block = 128 q.
// ---------------------------------------------------------------------------
__global__ __launch_bounds__(256) void attention_mfma(const bf16* __restrict__ QK,
                                                      const bf16* __restrict__ vT,
                                                      bf16* __restrict__ Pad) {
    int blk = blockIdx.x;
    int qt = blk & 7;                 // 8 q-blocks of 128 per (b,h)
    int bh = blk >> 3;
    int h = bh & (HEADS - 1), b = bh >> 3;
    int tid = threadIdx.x;
    int wave = tid >> 6, lane = tid & 63;
    int l15 = lane & 15, quad = lane >> 4;

    // K tile: 64 toks x 64 ch (rows 128B, swizzled); V^T tile: 64 d x 64 toks
    __shared__ __align__(16) bf16 KT[2][4096];
    __shared__ __align__(16) bf16 VTs[2][4096];

    const size_t base = (size_t)b * Ss * QKS + h * DHEAD;
    const bf16* kbase = QK + base + 512;

    int q0 = qt * 128 + wave * 32;    // wave's 32 q-rows (2 sub-blocks of 16)
    const bf16* qrow = QK + base + (size_t)(q0 + l15) * QKS + quad * 8;
    short8 qfA0 = *(const short8*)(qrow);
    short8 qfA1 = *(const short8*)(qrow + 32);
    short8 qfB0 = *(const short8*)(qrow + 16 * QKS);
    short8 qfB1 = *(const short8*)(qrow + 16 * QKS + 32);

    // staging geometry: chunks c=tid (rows 0..31) and c=tid+256 (rows 32..63)
    // chunk c -> (row=c>>3, col16=c&7); source col16 pre-swizzled ^ (row&7)
    int r1 = tid >> 3,         f1 = (tid & 7) ^ (r1 & 7);
    int r2 = (tid + 256) >> 3, f2 = ((tid + 256) & 7) ^ (r2 & 7);
    const bf16* gk1 = kbase + (size_t)r1 * QKS + f1 * 8;
    const bf16* gk2 = kbase + (size_t)r2 * QKS + f2 * 8;
    const bf16* gv1 = vT + (size_t)(h * 64 + r1) * 16384 + b * 1024 + f1 * 8;
    const bf16* gv2 = vT + (size_t)(h * 64 + r2) * 16384 + b * 1024 + f2 * 8;

    f32x4 oacc0[4] = {{0.f,0.f,0.f,0.f},{0.f,0.f,0.f,0.f},{0.f,0.f,0.f,0.f},{0.f,0.f,0.f,0.f}};
    f32x4 oacc1[4] = {{0.f,0.f,0.f,0.f},{0.f,0.f,0.f,0.f},{0.f,0.f,0.f,0.f},{0.f,0.f,0.f,0.f}};
    float lsum0 = 0.f, lsum1 = 0.f;
    const f32x4 zero4 = {0.f, 0.f, 0.f, 0.f};
    int srcA = ((quad & 1) * 2) * 16 + l15;   // P^T exchange source lanes
    int srcB = srcA + 16;
    bool hiq = (quad >= 2);
    int sw = l15 & 7;                          // read-side swizzle key

    auto stage = [&](int c0, int p) {
        stage16(gk1 + (size_t)c0 * QKS, &KT[p][wave * 512]);
        stage16(gk2 + (size_t)c0 * QKS, &KT[p][2048 + wave * 512]);
        stage16(gv1 + c0,               &VTs[p][wave * 512]);
        stage16(gv2 + c0,               &VTs[p][2048 + wave * 512]);
    };

    stage(0, 0);
    for (int it = 0; it < 16; ++it) {
        int p = it & 1;
        if (it + 1 < 16) {
            stage((it + 1) * 64, p ^ 1);
            asm volatile("s_waitcnt vmcnt(4)" ::: "memory");  // buf p landed; next in flight
        } else {
            asm volatile("s_waitcnt vmcnt(0)" ::: "memory");
        }
        __builtin_amdgcn_s_barrier();
        __builtin_amdgcn_sched_barrier(0);

        // ---- swapped QK^T over 64 toks x 32 q: K-frags read ONCE, used for
        //      both q sub-blocks. Lane holds S^T[t=kb*16+quad*4+r][q=l15].
        unsigned int pk0[4][2], pk1[4][2];
        __builtin_amdgcn_s_setprio(1);
#pragma unroll
        for (int kb = 0; kb < 4; kb++) {
            const bf16* kr = &KT[p][(kb * 16 + l15) * 64];
            short8 kf0 = *(const short8*)(kr + ((quad ^ sw) * 8));
            short8 kf1 = *(const short8*)(kr + (((4 + quad) ^ sw) * 8));
            f32x4 s0 = __builtin_amdgcn_mfma_f32_16x16x32_bf16(kf0, qfA0, zero4, 0, 0, 0);
            s0 = __builtin_amdgcn_mfma_f32_16x16x32_bf16(kf1, qfA1, s0, 0, 0, 0);
            f32x4 s1 = __builtin_amdgcn_mfma_f32_16x16x32_bf16(kf0, qfB0, zero4, 0, 0, 0);
            s1 = __builtin_amdgcn_mfma_f32_16x16x32_bf16(kf1, qfB1, s1, 0, 0, 0);
            float a0 = __expf(s0[0] * 0.125f);
            float a1 = __expf(s0[1] * 0.125f);
            float a2 = __expf(s0[2] * 0.125f);
            float a3 = __expf(s0[3] * 0.125f);
            lsum0 += (a0 + a1) + (a2 + a3);
            pk0[kb][0] = pkbf(a0, a1);
            pk0[kb][1] = pkbf(a2, a3);
            float b0 = __expf(s1[0] * 0.125f);
            float b1 = __expf(s1[1] * 0.125f);
            float b2 = __expf(s1[2] * 0.125f);
            float b3 = __expf(s1[3] * 0.125f);
            lsum1 += (b0 + b1) + (b2 + b3);
            pk1[kb][0] = pkbf(b0, b1);
            pk1[kb][1] = pkbf(b2, b3);
        }
        __builtin_amdgcn_s_setprio(0);

        // ---- quad exchange per q sub-block: P^T B-frags for t halves
        union { short8 s8; unsigned int u[4]; } PT00, PT01, PT10, PT11;
        {
            unsigned int A0 = __shfl((int)pk0[0][0], srcA), A1 = __shfl((int)pk0[0][1], srcA);
            unsigned int A2 = __shfl((int)pk0[1][0], srcA), A3 = __shfl((int)pk0[1][1], srcA);
            unsigned int B0 = __shfl((int)pk0[0][0], srcB), B1 = __shfl((int)pk0[0][1], srcB);
            unsigned int B2 = __shfl((int)pk0[1][0], srcB), B3 = __shfl((int)pk0[1][1], srcB);
            PT00.u[0] = hiq ? A2 : A0;  PT00.u[1] = hiq ? A3 : A1;
            PT00.u[2] = hiq ? B2 : B0;  PT00.u[3] = hiq ? B3 : B1;
            unsigned int C0 = __shfl((int)pk0[2][0], srcA), C1 = __shfl((int)pk0[2][1], srcA);
            unsigned int C2 = __shfl((int)pk0[3][0], srcA), C3 = __shfl((int)pk0[3][1], srcA);
            unsigned int D0 = __shfl((int)pk0[2][0], srcB), D1 = __shfl((int)pk0[2][1], srcB);
            unsigned int D2 = __shfl((int)pk0[3][0], srcB), D3 = __shfl((int)pk0[3][1], srcB);
            PT01.u[0] = hiq ? C2 : C0;  PT01.u[1] = hiq ? C3 : C1;
            PT01.u[2] = hiq ? D2 : D0;  PT01.u[3] = hiq ? D3 : D1;
        }
        {
            unsigned int A0 = __shfl((int)pk1[0][0], srcA), A1 = __shfl((int)pk1[0][1], srcA);
            unsigned int A2 = __shfl((int)pk1[1][0], srcA), A3 = __shfl((int)pk1[1][1], srcA);
            unsigned int B0 = __shfl((int)pk1[0][0], srcB), B1 = __shfl((int)pk1[0][1], srcB);
            unsigned int B2 = __shfl((int)pk1[1][0], srcB), B3 = __shfl((int)pk1[1][1], srcB);
            PT10.u[0] = hiq ? A2 : A0;  PT10.u[1] = hiq ? A3 : A1;
            PT10.u[2] = hiq ? B2 : B0;  PT10.u[3] = hiq ? B3 : B1;
            unsigned int C0 = __shfl((int)pk1[2][0], srcA), C1 = __shfl((int)pk1[2][1], srcA);
            unsigned int C2 = __shfl((int)pk1[3][0], srcA), C3 = __shfl((int)pk1[3][1], srcA);
            unsigned int D0 = __shfl((int)pk1[2][0], srcB), D1 = __shfl((int)pk1[2][1], srcB);
            unsigned int D2 = __shfl((int)pk1[3][0], srcB), D3 = __shfl((int)pk1[3][1], srcB);
            PT11.u[0] = hiq ? C2 : C0;  PT11.u[1] = hiq ? C3 : C1;
            PT11.u[2] = hiq ? D2 : D0;  PT11.u[3] = hiq ? D3 : D1;
        }

        // ---- PV: O^T += V^T . P^T — V-frags read ONCE, used for both q-blocks
        __builtin_amdgcn_s_setprio(1);
#pragma unroll
        for (int dt = 0; dt < 4; dt++) {
            const bf16* vr = &VTs[p][(dt * 16 + l15) * 64];
            short8 vf0 = *(const short8*)(vr + ((quad ^ sw) * 8));
            short8 vf1 = *(const short8*)(vr + (((4 + quad) ^ sw) * 8));
            oacc0[dt] = __builtin_amdgcn_mfma_f32_16x16x32_bf16(vf0, PT00.s8, oacc0[dt], 0, 0, 0);
            oacc0[dt] = __builtin_amdgcn_mfma_f32_16x16x32_bf16(vf1, PT01.s8, oacc0[dt], 0, 0, 0);
            oacc1[dt] = __builtin_amdgcn_mfma_f32_16x16x32_bf16(vf0, PT10.s8, oacc1[dt], 0, 0, 0);
            oacc1[dt] = __builtin_amdgcn_mfma_f32_16x16x32_bf16(vf1, PT11.s8, oacc1[dt], 0, 0, 0);
        }
        __builtin_amdgcn_s_setprio(0);

        __builtin_amdgcn_sched_barrier(0);   // pin reads above read-done barrier
        __builtin_amdgcn_s_barrier();        // read-done: next iter may overwrite buf p
        __builtin_amdgcn_sched_barrier(0);   // pin next stage below
    }

    // denoms for q=l15 of each sub-block: sum partials across the 4 quads
    lsum0 += __shfl_xor(lsum0, 16);
    lsum0 += __shfl_xor(lsum0, 32);
    lsum1 += __shfl_xor(lsum1, 16);
    lsum1 += __shfl_xor(lsum1, 32);
    float inv0 = 1.f / lsum0;
    float inv1 = 1.f / lsum1;

    {
        int s = q0 + l15;
        size_t rowoff = ((size_t)(b * PROW + (s >> 5) + 1) * PROW + (s & 31) + 1) * Cc + h * DHEAD;
#pragma unroll
        for (int dt = 0; dt < 4; dt++) {
            B4 o;
#pragma unroll
            for (int r = 0; r < 4; r++) o.h[r] = __float2bfloat16(oacc0[dt][r] * inv0);
            *(ushort4*)(Pad + rowoff + dt * 16 + quad * 4) = o.u;
        }
    }
    {
        int s = q0 + 16 + l15;
        size_t rowoff = ((size_t)(b * PROW + (s >> 5) + 1) * PROW + (s & 31) + 1) * Cc + h * DHEAD;
#pragma unroll
        for (int dt = 0; dt < 4; dt++) {
            B4 o;
#pragma unroll
            for (int r = 0; r < 4; r++) o.h[r] = __float2bfloat16(oacc1[dt][r] * inv1);
            *(ushort4*)(Pad + rowoff + dt * 16 + quad * 4) = o.u;
        }
    }
}

// ---------------------------------------------------------------------------
// 5) 3x3 conv as implicit GEMM, dx-tap sharing + 2-phase counted-vmcnt
//    double-buffer + T2 pair-row XOR swizzle on BOTH tiles (unchanged r5).
// ---------------------------------------------------------------------------
__global__ __launch_bounds__(256, 2) void conv_mfma(const bf16* __restrict__ Pad,
                                                    const bf16* __restrict__ Wct,
                                                    const float* __restrict__ bias,
                                                    const float* __restrict__ xres,
                                                    float* __restrict__ out) {
    // A halo tile: 136 tokens x 32 k = 68 lines x 128B ; B: 3 taps x 128 x 32
    __shared__ __align__(16) bf16 As[2][136 * 32];
    __shared__ __align__(16) bf16 Bs[2][3 * 4096];

    int tid = threadIdx.x;
    int wave = tid >> 6, lane = tid & 63;
    int l15 = lane & 15, quad = lane >> 4;
    int wm = wave >> 1, wn = wave & 1;
    int m0 = blockIdx.y * 128, n0 = blockIdx.x * 128;
    int b = m0 >> 10, oh0 = (m0 & 1023) >> 5;      // block = 4 image rows of one batch

    // ---- A staging: swizzle-decoded per-lane source (linear LDS dest) ----
    int rA1, cA1, rA2, cA2, rA3, cA3;
    swz_decode(tid,              rA1, cA1);
    swz_decode(tid + 256,        rA2, cA2);
    swz_decode((tid & 31) + 512, rA3, cA3);        // only staged when tid<32
    int rr1 = rA1 / 34, co1 = rA1 - rr1 * 34;
    int rr2 = rA2 / 34, co2 = rA2 - rr2 * 34;
    int rr3 = rA3 / 34, co3 = rA3 - rr3 * 34;
    const size_t dyStride = (size_t)PROW * Cc;
    const bf16* pA1 = Pad + ((size_t)b * PIMG + (size_t)(oh0 + rr1) * PROW + co1) * Cc + cA1 * 8;
    const bf16* pA2 = Pad + ((size_t)b * PIMG + (size_t)(oh0 + rr2) * PROW + co2) * Cc + cA2 * 8;
    const bf16* pA3 = Pad + ((size_t)b * PIMG + (size_t)(oh0 + rr3) * PROW + co3) * Cc + cA3 * 8;

    // ---- B staging: swizzle-decoded per-lane source ----
    int rB1, cB1, rB2, cB2;
    swz_decode(wave * 128 + lane,      rB1, cB1);
    swz_decode(wave * 128 + 64 + lane, rB2, cB2);
    const bf16* gw1 = Wct + (size_t)(n0 + rB1) * Cc + cB1 * 8;
    const bf16* gw2 = Wct + (size_t)(n0 + rB2) * Cc + cB2 * 8;

    // ---- precomputed swizzled read offsets (bf16 elems) ----
    int aoff[3][4], boff[4];
#pragma unroll
    for (int mt = 0; mt < 4; mt++) {
        int rbase = (wm * 2 + (mt >> 1)) * 34 + (mt & 1) * 16 + l15;
#pragma unroll
        for (int dxi = 0; dxi < 3; dxi++) aoff[dxi][mt] = swz_off(rbase + dxi, quad);
    }
#pragma unroll
    for (int nt = 0; nt < 4; nt++) boff[nt] = swz_off(wn * 64 + nt * 16 + l15, quad);

    // stage iteration 'it' (dyi = it>>4, k0 = (it&15)*32) into buffer p
    // wave0 issues 9 vmem ops, waves1-3 issue 8 -> uniform vmcnt(8) is safe
    auto stage_it = [&](int it, int p) {
        int dyi = it >> 4;
        int k0 = (it & 15) << 5;
        size_t ag = (size_t)dyi * dyStride + k0;
        stage16(pA1 + ag, &As[p][wave * 512]);
        stage16(pA2 + ag, &As[p][2048 + wave * 512]);
        if (tid < 32) stage16(pA3 + ag, &As[p][4096]);
        size_t wg = (size_t)(dyi * 3) * (Cc * Cc) + k0;
#pragma unroll
        for (int t = 0; t < 3; t++) {
            size_t tg = wg + (size_t)t * (Cc * Cc);
            stage16(gw1 + tg, &Bs[p][t * 4096 + wave * 1024]);
            stage16(gw2 + tg, &Bs[p][t * 4096 + wave * 1024 + 512]);
        }
    };

    f32x4 acc[4][4] = {};
    stage_it(0, 0);
    for (int it = 0; it < 48; ++it) {
        int p = it & 1;
        if (it + 1 < 48) {
            stage_it(it + 1, p ^ 1);
            asm volatile("s_waitcnt vmcnt(8)" ::: "memory");   // this tile landed; next stays in flight
        } else {
            asm volatile("s_waitcnt vmcnt(0)" ::: "memory");
        }
        __builtin_amdgcn_s_barrier();                          // all waves: buf[p] staged

        short8 af[3][4], bfv[3][4];
#pragma unroll
        for (int dxi = 0; dxi < 3; dxi++) {
#pragma unroll
            for (int mt = 0; mt < 4; mt++)
                af[dxi][mt] = *(const short8*)&As[p][aoff[dxi][mt]];
#pragma unroll
            for (int nt = 0; nt < 4; nt++)
                bfv[dxi][nt] = *(const short8*)&Bs[p][dxi * 4096 + boff[nt]];
        }
        asm volatile("s_waitcnt lgkmcnt(0)" ::: "memory");     // reads landed in regs
        __builtin_amdgcn_sched_barrier(0);                     // rule #18: pin MFMA below
        __builtin_amdgcn_s_barrier();                          // read-done: next stage may overwrite buf[p]

#pragma unroll
        for (int dxi = 0; dxi < 3; dxi++)
#pragma unroll
            for (int mt = 0; mt < 4; mt++)
#pragma unroll
                for (int nt = 0; nt < 4; nt++)
                    acc[mt][nt] = __builtin_amdgcn_mfma_f32_16x16x32_bf16(af[dxi][mt], bfv[dxi][nt], acc[mt][nt], 0, 0, 0);
    }

#pragma unroll
    for (int mt = 0; mt < 4; mt++)
#pragma unroll
        for (int r = 0; r < 4; r++) {
            size_t row = (size_t)(m0 + wm * 64 + mt * 16 + quad * 4 + r) * Cc + n0 + wn * 64 + l15;
#pragma unroll
            for (int nt = 0; nt < 4; nt++) {
                int n = n0 + wn * 64 + nt * 16 + l15;
                out[row + nt * 16] = acc[mt][nt][r] + bias[n] + xres[row + nt * 16];
            }
        }
}

// ---------------------------------------------------------------------------
extern "C" void kernel_launch(void* const* d_in, const int* in_sizes, int n_in,
                              void* d_out, int out_size, void* d_ws, size_t ws_size,
                              hipStream_t stream) {
    const float* x     = (const float*)d_in[0];
    const float* gamma = (const float*)d_in[1];
    const float* beta  = (const float*)d_in[2];
    const float* wq    = (const float*)d_in[3];
    const float* wk    = (const float*)d_in[4];
    const float* wv    = (const float*)d_in[5];
    const float* convw = (const float*)d_in[6];
    const float* convb = (const float*)d_in[7];
    float* out = (float*)d_out;

    // ws layout (time-multiplexed; peak ~71.5 MiB):
    //   [0, 18.9 MiB)  : pad   (written by zero_pad+attention AFTER gemm_qkv)
    //   [0, 4 KiB)     : stats (dead before pad is written)
    //   [4 KiB, +16MiB): xn    (dead before pad is written)
    //   [xn end, +1.5M): wt    (dead before pad is written)
    //   [19 MiB, +32M) : qk    (Q,K rows, stride 1024)
    //   [51 MiB, +16M) : vT    (V transposed [h][d][b*1024+tok])
    //   [67 MiB, +4.5M): wct
    char* ws = (char*)d_ws;
    bf16*  pad   = (bf16*)ws;
    float* stats = (float*)ws;
    bf16*  xn    = (bf16*)(ws + 4096);
    bf16*  wt    = (bf16*)(ws + 4096 + ((size_t)16 << 20));
    bf16*  qk    = (bf16*)(ws + ((size_t)19 << 20));
    bf16*  vt    = (bf16*)(ws + ((size_t)51 << 20));
    bf16*  wct   = (bf16*)(ws + ((size_t)67 << 20));

    // weight prep (dst regions distinct from src-time-live data)
    wtrans<<<dim3(128, 1), 256, 0, stream>>>(wq, wt);
    wtrans<<<dim3(128, 1), 256, 0, stream>>>(wk, wt + 262144);
    wtrans<<<dim3(128, 1), 256, 0, stream>>>(wv, wt + 524288);
    wtrans<<<dim3(128, 9), 256, 0, stream>>>(convw, wct);

    gn_stats<<<dim3(Bn * GROUPS), 256, 0, stream>>>(x, stats);
    gn_apply<<<dim3(Mtok * Cc / (4 * 256)), 256, 0, stream>>>(x, stats, gamma, beta, xn);

    gemm_qkv<<<dim3(QKVS / 128, Mtok / 128), 256, 0, stream>>>(xn, wt, qk, vt);

    zero_pad<<<dim3(528), 256, 0, stream>>>(pad);   // after gemm_qkv: region overlaps xn/wt
    attention_mfma<<<dim3(Bn * HEADS * (Ss / 128)), 256, 0, stream>>>(qk, vt, pad);

    conv_mfma<<<dim3(Cc / 128, Mtok / 128), 256, 0, stream>>>(pad, wct, convb, x, out);
}

// Round 7
// 314.286 us; speedup vs baseline: 1.0149x; 1.0149x over previous
//
#include <hip/hip_runtime.h>
#include <hip/hip_bf16.h>

// Problem constants
#define Bn 16
#define Cc 512
#define Ss 1024           // H*W tokens per batch
#define HEADS 8
#define DHEAD 64
#define GROUPS 32
#define CPG 16
#define EPSv 1e-5f
#define Mtok (Bn*Ss)      // 16384 token rows
#define QKVS 1536         // (legacy) fused qkv row stride
#define QKS 1024          // Q+K row stride (V split out transposed)
#define PROW 34           // padded image row (32 + halo)
#define PIMG (PROW*PROW)  // 1156 padded tokens per batch

typedef __hip_bfloat16 bf16;
typedef __attribute__((ext_vector_type(8))) short short8;   // MFMA A/B frag (8 bf16)
typedef __attribute__((ext_vector_type(4))) float f32x4;    // MFMA C/D frag

union U4 { uint4 u; bf16 h[8]; };
union B4 { ushort4 u; bf16 h[4]; };

// async global->LDS, 16 B/lane; LDS dest = wave-uniform base + lane*16
__device__ __forceinline__ void stage16(const bf16* g, bf16* l) {
    __builtin_amdgcn_global_load_lds((const __attribute__((address_space(1))) void*)g,
                                     (__attribute__((address_space(3))) void*)l,
                                     16, 0, 0);
}

// pack two f32 -> one dword of 2 bf16 (lo=a, hi=b)
__device__ __forceinline__ unsigned int pkbf(float a, float b) {
    union { __hip_bfloat16 h; unsigned short u; } ua, ub;
    ua.h = __float2bfloat16(a); ub.h = __float2bfloat16(b);
    return ((unsigned int)ub.u << 16) | ua.u;
}

// ---- T2 pair-row XOR swizzle (128-B lines of 8 x 16-B chunks) ----
// logical (row r, chunk c) stored at line=r>>1, pos=((r&1)*4+c)^(line&7)
__device__ __forceinline__ void swz_decode(int F, int& r, int& c) {
    int line = F >> 3, pos = F & 7;
    int u = pos ^ (line & 7);
    r = (line << 1) | (u >> 2);
    c = u & 3;
}
// read offset in bf16 elems for logical (r, chunk q)
__device__ __forceinline__ int swz_off(int r, int q) {
    return (r >> 1) * 64 + (((((r & 1) << 2) + q) ^ ((r >> 1) & 7)) << 3);
}

// ---------------------------------------------------------------------------
// 0) Weight transpose+convert: src f32 [512][512] (k-major) -> dst bf16 [n][k]
// ---------------------------------------------------------------------------
__global__ __launch_bounds__(256) void wtrans(const float* __restrict__ src,
                                              bf16* __restrict__ dst) {
    size_t off = (size_t)blockIdx.y * 262144;
    int t = blockIdx.x * 256 + threadIdx.x;     // 0..32767
    int n = t & 511, k8 = (t >> 9) * 8;
    const float* s = src + off + (size_t)k8 * 512 + n;
    U4 o;
#pragma unroll
    for (int j = 0; j < 8; j++) o.h[j] = __float2bfloat16(s[(size_t)j * 512]);
    *(uint4*)(dst + off + (size_t)n * 512 + k8) = o.u;
}

// ---------------------------------------------------------------------------
// 1) GroupNorm stats
// ---------------------------------------------------------------------------
__global__ __launch_bounds__(256) void gn_stats(const float* __restrict__ x,
                                                float* __restrict__ stats) {
    int bg = blockIdx.x;
    int b = bg >> 5, g = bg & 31;
    int tid = threadIdx.x;
    const size_t base = (size_t)b * Ss * Cc + g * CPG;
    float sum = 0.f, sq = 0.f;
    for (int i = tid; i < 4096; i += 256) {
        int s = i >> 2, c4 = (i & 3) * 4;
        float4 t = *(const float4*)(x + base + (size_t)s * Cc + c4);
        sum += t.x + t.y + t.z + t.w;
        sq  += t.x * t.x + t.y * t.y + t.z * t.z + t.w * t.w;
    }
    __shared__ float s1[4], s2[4];
#pragma unroll
    for (int off = 32; off > 0; off >>= 1) {
        sum += __shfl_down(sum, off);
        sq  += __shfl_down(sq,  off);
    }
    if ((tid & 63) == 0) { s1[tid >> 6] = sum; s2[tid >> 6] = sq; }
    __syncthreads();
    if (tid == 0) {
        float S = s1[0] + s1[1] + s1[2] + s1[3];
        float Q = s2[0] + s2[1] + s2[2] + s2[3];
        float mean = S * (1.f / 16384.f);
        float var  = Q * (1.f / 16384.f) - mean * mean;
        stats[bg * 2 + 0] = mean;
        stats[bg * 2 + 1] = rsqrtf(var + EPSv);
    }
}

// ---------------------------------------------------------------------------
// 2) GroupNorm apply (f32 in, bf16 out)
// ---------------------------------------------------------------------------
__global__ __launch_bounds__(256) void gn_apply(const float* __restrict__ x,
                                                const float* __restrict__ stats,
                                                const float* __restrict__ gamma,
                                                const float* __restrict__ beta,
                                                bf16* __restrict__ xn) {
    size_t i = (size_t)blockIdx.x * 256 + threadIdx.x;
    size_t e = i * 4;
    int c0 = (int)(e & (Cc - 1));
    int token = (int)(e >> 9);
    int b = token >> 10;
    int g = c0 >> 4;
    float mean = stats[(b * 32 + g) * 2 + 0];
    float rstd = stats[(b * 32 + g) * 2 + 1];
    float4 t  = *(const float4*)(x + e);
    float4 gm = *(const float4*)(gamma + c0);
    float4 bt = *(const float4*)(beta + c0);
    B4 o;
    o.h[0] = __float2bfloat16((t.x - mean) * rstd * gm.x + bt.x);
    o.h[1] = __float2bfloat16((t.y - mean) * rstd * gm.y + bt.y);
    o.h[2] = __float2bfloat16((t.z - mean) * rstd * gm.z + bt.z);
    o.h[3] = __float2bfloat16((t.w - mean) * rstd * gm.w + bt.w);
    *(ushort4*)(xn + e) = o.u;
}

// ---------------------------------------------------------------------------
// 2b) Zero the padded-activation border (132 border tokens x 512 ch x 16 b)
// ---------------------------------------------------------------------------
__global__ __launch_bounds__(256) void zero_pad(bf16* __restrict__ Pad) {
    int idx = blockIdx.x * 256 + threadIdx.x;     // exactly 16*132*64
    int b = idx / (132 * 64);
    int rem = idx - b * 132 * 64;
    int t = rem >> 6, seg = rem & 63;
    int r, c;
    if (t < 34)      { r = 0;  c = t; }
    else if (t < 68) { r = 33; c = t - 34; }
    else { int u = t - 68; r = 1 + (u >> 1); c = (u & 1) * 33; }
    uint4 z = {0u, 0u, 0u, 0u};
    *(uint4*)(Pad + ((size_t)b * PIMG + r * PROW + c) * Cc + seg * 8) = z;
}

// ---------------------------------------------------------------------------
// 3) Fused QKV GEMM: 128x128 tile + 2-phase counted-vmcnt DOUBLE-BUFFER
//    (conv-proven pipeline). Q,K -> QK buffer (row stride 1024);
//    V -> TRANSPOSED buffer vT[h][d][b*1024+tok] (packed 8B stores along tok).
// ---------------------------------------------------------------------------
__global__ __launch_bounds__(256) void gemm_qkv(const bf16* __restrict__ A,
                                                const bf16* __restrict__ Wt,
                                                bf16* __restrict__ C,
                                                bf16* __restrict__ vT) {
    __shared__ __align__(16) bf16 As[2][4096];
    __shared__ __align__(16) bf16 Bs[2][4096];
    int tid = threadIdx.x;
    int wave = tid >> 6, lane = tid & 63;
    int l15 = lane & 15, quad = lane >> 4;
    int wm = wave >> 1, wn = wave & 1;
    int m0 = blockIdx.y * 128, n0 = blockIdx.x * 128;
    int lr = lane >> 2, kseg = (lane & 3) * 8;
    int ar0 = wave * 32 + lr;                      // tile row staged by this lane

    const bf16* ga = A  + (size_t)(m0 + ar0) * Cc + kseg;
    const bf16* gb = Wt + (size_t)(n0 + ar0) * Cc + kseg;

    // each thread stages 4 chunks/tile -> after issuing next tile's 4,
    // vmcnt(4) == current tile fully landed
    auto stageg = [&](int k0, int p) {
        stage16(ga + k0,                   &As[p][wave * 1024]);
        stage16(ga + k0 + (size_t)16 * Cc, &As[p][wave * 1024 + 512]);
        stage16(gb + k0,                   &Bs[p][wave * 1024]);
        stage16(gb + k0 + (size_t)16 * Cc, &Bs[p][wave * 1024 + 512]);
    };

    f32x4 acc[4][4] = {};
    stageg(0, 0);
    for (int it = 0; it < 16; ++it) {
        int p = it & 1;
        if (it + 1 < 16) {
            stageg((it + 1) * 32, p ^ 1);
            asm volatile("s_waitcnt vmcnt(4)" ::: "memory");   // this tile landed; next in flight
        } else {
            asm volatile("s_waitcnt vmcnt(0)" ::: "memory");
        }
        __builtin_amdgcn_s_barrier();                          // buf[p] staged

        short8 af[4], bfv[4];
#pragma unroll
        for (int mt = 0; mt < 4; mt++) af[mt]  = *(const short8*)&As[p][(wm * 64 + mt * 16 + l15) * 32 + quad * 8];
#pragma unroll
        for (int nt = 0; nt < 4; nt++) bfv[nt] = *(const short8*)&Bs[p][(wn * 64 + nt * 16 + l15) * 32 + quad * 8];
        asm volatile("s_waitcnt lgkmcnt(0)" ::: "memory");     // reads landed in regs
        __builtin_amdgcn_sched_barrier(0);
        __builtin_amdgcn_s_barrier();                          // read-done: next stage may overwrite

        __builtin_amdgcn_s_setprio(1);
#pragma unroll
        for (int mt = 0; mt < 4; mt++)
#pragma unroll
            for (int nt = 0; nt < 4; nt++)
                acc[mt][nt] = __builtin_amdgcn_mfma_f32_16x16x32_bf16(af[mt], bfv[nt], acc[mt][nt], 0, 0, 0);
        __builtin_amdgcn_s_setprio(0);
    }

    if (n0 < 1024) {
        // Q/K: normal store, row stride QKS
#pragma unroll
        for (int mt = 0; mt < 4; mt++)
#pragma unroll
            for (int r = 0; r < 4; r++) {
                size_t row = (size_t)(m0 + wm * 64 + mt * 16 + quad * 4 + r) * QKS + n0 + wn * 64 + l15;
#pragma unroll
                for (int nt = 0; nt < 4; nt++)
                    C[row + nt * 16] = __float2bfloat16(acc[mt][nt][r]);
            }
    } else {
        // V: transposed store vT[(h*64+d)][b*1024 + tok], 8B packed along tok
        int hh = ((n0 - 1024) >> 6) + wn;          // head
        int bq = m0 >> 10;
        int tok0 = (m0 & 1023) + wm * 64;
#pragma unroll
        for (int nt = 0; nt < 4; nt++) {
            int d = nt * 16 + l15;
            bf16* drow = vT + (size_t)(hh * 64 + d) * 16384 + bq * 1024 + tok0;
#pragma unroll
            for (int mt = 0; mt < 4; mt++) {
                B4 o;
#pragma unroll
                for (int r = 0; r < 4; r++) o.h[r] = __float2bfloat16(acc[mt][nt][r]);
                *(ushort4*)(drow + mt * 16 + quad * 4) = o.u;
            }
        }
    }
}

// ---------------------------------------------------------------------------
// 4) Flash-style MFMA attention, KVBLK=64, 2-phase counted-vmcnt dbuf,
//    Q-blocked (32 q-rows/wave). Unchanged from round 6.
// ---------------------------------------------------------------------------
__global__ __launch_bounds__(256) void attention_mfma(const bf16* __restrict__ QK,
                                                      const bf16* __restrict__ vT,
                                                      bf16* __restrict__ Pad) {
    int blk = blockIdx.x;
    int qt = blk & 7;                 // 8 q-blocks of 128 per (b,h)
    int bh = blk >> 3;
    int h = bh & (HEADS - 1), b = bh >> 3;
    int tid = threadIdx.x;
    int wave = tid >> 6, lane = tid & 63;
    int l15 = lane & 15, quad = lane >> 4;

    // K tile: 64 toks x 64 ch (rows 128B, swizzled); V^T tile: 64 d x 64 toks
    __shared__ __align__(16) bf16 KT[2][4096];
    __shared__ __align__(16) bf16 VTs[2][4096];

    const size_t base = (size_t)b * Ss * QKS + h * DHEAD;
    const bf16* kbase = QK + base + 512;

    int q0 = qt * 128 + wave * 32;    // wave's 32 q-rows (2 sub-blocks of 16)
    const bf16* qrow = QK + base + (size_t)(q0 + l15) * QKS + quad * 8;
    short8 qfA0 = *(const short8*)(qrow);
    short8 qfA1 = *(const short8*)(qrow + 32);
    short8 qfB0 = *(const short8*)(qrow + 16 * QKS);
    short8 qfB1 = *(const short8*)(qrow + 16 * QKS + 32);

    // staging geometry: chunks c=tid (rows 0..31) and c=tid+256 (rows 32..63)
    // chunk c -> (row=c>>3, col16=c&7); source col16 pre-swizzled ^ (row&7)
    int r1 = tid >> 3,         f1 = (tid & 7) ^ (r1 & 7);
    int r2 = (tid + 256) >> 3, f2 = ((tid + 256) & 7) ^ (r2 & 7);
    const bf16* gk1 = kbase + (size_t)r1 * QKS + f1 * 8;
    const bf16* gk2 = kbase + (size_t)r2 * QKS + f2 * 8;
    const bf16* gv1 = vT + (size_t)(h * 64 + r1) * 16384 + b * 1024 + f1 * 8;
    const bf16* gv2 = vT + (size_t)(h * 64 + r2) * 16384 + b * 1024 + f2 * 8;

    f32x4 oacc0[4] = {{0.f,0.f,0.f,0.f},{0.f,0.f,0.f,0.f},{0.f,0.f,0.f,0.f},{0.f,0.f,0.f,0.f}};
    f32x4 oacc1[4] = {{0.f,0.f,0.f,0.f},{0.f,0.f,0.f,0.f},{0.f,0.f,0.f,0.f},{0.f,0.f,0.f,0.f}};
    float lsum0 = 0.f, lsum1 = 0.f;
    const f32x4 zero4 = {0.f, 0.f, 0.f, 0.f};
    int srcA = ((quad & 1) * 2) * 16 + l15;   // P^T exchange source lanes
    int srcB = srcA + 16;
    bool hiq = (quad >= 2);
    int sw = l15 & 7;                          // read-side swizzle key

    auto stage = [&](int c0, int p) {
        stage16(gk1 + (size_t)c0 * QKS, &KT[p][wave * 512]);
        stage16(gk2 + (size_t)c0 * QKS, &KT[p][2048 + wave * 512]);
        stage16(gv1 + c0,               &VTs[p][wave * 512]);
        stage16(gv2 + c0,               &VTs[p][2048 + wave * 512]);
    };

    stage(0, 0);
    for (int it = 0; it < 16; ++it) {
        int p = it & 1;
        if (it + 1 < 16) {
            stage((it + 1) * 64, p ^ 1);
            asm volatile("s_waitcnt vmcnt(4)" ::: "memory");  // buf p landed; next in flight
        } else {
            asm volatile("s_waitcnt vmcnt(0)" ::: "memory");
        }
        __builtin_amdgcn_s_barrier();
        __builtin_amdgcn_sched_barrier(0);

        // ---- swapped QK^T over 64 toks x 32 q: K-frags read ONCE, used for
        //      both q sub-blocks. Lane holds S^T[t=kb*16+quad*4+r][q=l15].
        unsigned int pk0[4][2], pk1[4][2];
        __builtin_amdgcn_s_setprio(1);
#pragma unroll
        for (int kb = 0; kb < 4; kb++) {
            const bf16* kr = &KT[p][(kb * 16 + l15) * 64];
            short8 kf0 = *(const short8*)(kr + ((quad ^ sw) * 8));
            short8 kf1 = *(const short8*)(kr + (((4 + quad) ^ sw) * 8));
            f32x4 s0 = __builtin_amdgcn_mfma_f32_16x16x32_bf16(kf0, qfA0, zero4, 0, 0, 0);
            s0 = __builtin_amdgcn_mfma_f32_16x16x32_bf16(kf1, qfA1, s0, 0, 0, 0);
            f32x4 s1 = __builtin_amdgcn_mfma_f32_16x16x32_bf16(kf0, qfB0, zero4, 0, 0, 0);
            s1 = __builtin_amdgcn_mfma_f32_16x16x32_bf16(kf1, qfB1, s1, 0, 0, 0);
            float a0 = __expf(s0[0] * 0.125f);
            float a1 = __expf(s0[1] * 0.125f);
            float a2 = __expf(s0[2] * 0.125f);
            float a3 = __expf(s0[3] * 0.125f);
            lsum0 += (a0 + a1) + (a2 + a3);
            pk0[kb][0] = pkbf(a0, a1);
            pk0[kb][1] = pkbf(a2, a3);
            float b0 = __expf(s1[0] * 0.125f);
            float b1 = __expf(s1[1] * 0.125f);
            float b2 = __expf(s1[2] * 0.125f);
            float b3 = __expf(s1[3] * 0.125f);
            lsum1 += (b0 + b1) + (b2 + b3);
            pk1[kb][0] = pkbf(b0, b1);
            pk1[kb][1] = pkbf(b2, b3);
        }
        __builtin_amdgcn_s_setprio(0);

        // ---- quad exchange per q sub-block: P^T B-frags for t halves
        union { short8 s8; unsigned int u[4]; } PT00, PT01, PT10, PT11;
        {
            unsigned int A0 = __shfl((int)pk0[0][0], srcA), A1 = __shfl((int)pk0[0][1], srcA);
            unsigned int A2 = __shfl((int)pk0[1][0], srcA), A3 = __shfl((int)pk0[1][1], srcA);
            unsigned int B0 = __shfl((int)pk0[0][0], srcB), B1 = __shfl((int)pk0[0][1], srcB);
            unsigned int B2 = __shfl((int)pk0[1][0], srcB), B3 = __shfl((int)pk0[1][1], srcB);
            PT00.u[0] = hiq ? A2 : A0;  PT00.u[1] = hiq ? A3 : A1;
            PT00.u[2] = hiq ? B2 : B0;  PT00.u[3] = hiq ? B3 : B1;
            unsigned int C0 = __shfl((int)pk0[2][0], srcA), C1 = __shfl((int)pk0[2][1], srcA);
            unsigned int C2 = __shfl((int)pk0[3][0], srcA), C3 = __shfl((int)pk0[3][1], srcA);
            unsigned int D0 = __shfl((int)pk0[2][0], srcB), D1 = __shfl((int)pk0[2][1], srcB);
            unsigned int D2 = __shfl((int)pk0[3][0], srcB), D3 = __shfl((int)pk0[3][1], srcB);
            PT01.u[0] = hiq ? C2 : C0;  PT01.u[1] = hiq ? C3 : C1;
            PT01.u[2] = hiq ? D2 : D0;  PT01.u[3] = hiq ? D3 : D1;
        }
        {
            unsigned int A0 = __shfl((int)pk1[0][0], srcA), A1 = __shfl((int)pk1[0][1], srcA);
            unsigned int A2 = __shfl((int)pk1[1][0], srcA), A3 = __shfl((int)pk1[1][1], srcA);
            unsigned int B0 = __shfl((int)pk1[0][0], srcB), B1 = __shfl((int)pk1[0][1], srcB);
            unsigned int B2 = __shfl((int)pk1[1][0], srcB), B3 = __shfl((int)pk1[1][1], srcB);
            PT10.u[0] = hiq ? A2 : A0;  PT10.u[1] = hiq ? A3 : A1;
            PT10.u[2] = hiq ? B2 : B0;  PT10.u[3] = hiq ? B3 : B1;
            unsigned int C0 = __shfl((int)pk1[2][0], srcA), C1 = __shfl((int)pk1[2][1], srcA);
            unsigned int C2 = __shfl((int)pk1[3][0], srcA), C3 = __shfl((int)pk1[3][1], srcA);
            unsigned int D0 = __shfl((int)pk1[2][0], srcB), D1 = __shfl((int)pk1[2][1], srcB);
            unsigned int D2 = __shfl((int)pk1[3][0], srcB), D3 = __shfl((int)pk1[3][1], srcB);
            PT11.u[0] = hiq ? C2 : C0;  PT11.u[1] = hiq ? C3 : C1;
            PT11.u[2] = hiq ? D2 : D0;  PT11.u[3] = hiq ? D3 : D1;
        }

        // ---- PV: O^T += V^T . P^T — V-frags read ONCE, used for both q-blocks
        __builtin_amdgcn_s_setprio(1);
#pragma unroll
        for (int dt = 0; dt < 4; dt++) {
            const bf16* vr = &VTs[p][(dt * 16 + l15) * 64];
            short8 vf0 = *(const short8*)(vr + ((quad ^ sw) * 8));
            short8 vf1 = *(const short8*)(vr + (((4 + quad) ^ sw) * 8));
            oacc0[dt] = __builtin_amdgcn_mfma_f32_16x16x32_bf16(vf0, PT00.s8, oacc0[dt], 0, 0, 0);
            oacc0[dt] = __builtin_amdgcn_mfma_f32_16x16x32_bf16(vf1, PT01.s8, oacc0[dt], 0, 0, 0);
            oacc1[dt] = __builtin_amdgcn_mfma_f32_16x16x32_bf16(vf0, PT10.s8, oacc1[dt], 0, 0, 0);
            oacc1[dt] = __builtin_amdgcn_mfma_f32_16x16x32_bf16(vf1, PT11.s8, oacc1[dt], 0, 0, 0);
        }
        __builtin_amdgcn_s_setprio(0);

        __builtin_amdgcn_sched_barrier(0);   // pin reads above read-done barrier
        __builtin_amdgcn_s_barrier();        // read-done: next iter may overwrite buf p
        __builtin_amdgcn_sched_barrier(0);   // pin next stage below
    }

    // denoms for q=l15 of each sub-block: sum partials across the 4 quads
    lsum0 += __shfl_xor(lsum0, 16);
    lsum0 += __shfl_xor(lsum0, 32);
    lsum1 += __shfl_xor(lsum1, 16);
    lsum1 += __shfl_xor(lsum1, 32);
    float inv0 = 1.f / lsum0;
    float inv1 = 1.f / lsum1;

    {
        int s = q0 + l15;
        size_t rowoff = ((size_t)(b * PROW + (s >> 5) + 1) * PROW + (s & 31) + 1) * Cc + h * DHEAD;
#pragma unroll
        for (int dt = 0; dt < 4; dt++) {
            B4 o;
#pragma unroll
            for (int r = 0; r < 4; r++) o.h[r] = __float2bfloat16(oacc0[dt][r] * inv0);
            *(ushort4*)(Pad + rowoff + dt * 16 + quad * 4) = o.u;
        }
    }
    {
        int s = q0 + 16 + l15;
        size_t rowoff = ((size_t)(b * PROW + (s >> 5) + 1) * PROW + (s & 31) + 1) * Cc + h * DHEAD;
#pragma unroll
        for (int dt = 0; dt < 4; dt++) {
            B4 o;
#pragma unroll
            for (int r = 0; r < 4; r++) o.h[r] = __float2bfloat16(oacc1[dt][r] * inv1);
            *(ushort4*)(Pad + rowoff + dt * 16 + quad * 4) = o.u;
        }
    }
}

// ---------------------------------------------------------------------------
// 5) 3x3 conv as implicit GEMM, dx-tap sharing + 2-phase counted-vmcnt dbuf
//    + T2 swizzle + NEW: per-dxi phase interleave with counted lgkm waits:
//    reads(dxi0,1) -> MFMA(dxi0) -> reads(dxi2) -> MFMA(dxi1) -> lgkm(0) ->
//    read-done barrier -> MFMA(dxi2). Compiler auto-inserts fine lgkm waits
//    for the C++-visible deps; sched_barrier(0) pins the group structure.
// ---------------------------------------------------------------------------
__global__ __launch_bounds__(256, 2) void conv_mfma(const bf16* __restrict__ Pad,
                                                    const bf16* __restrict__ Wct,
                                                    const float* __restrict__ bias,
                                                    const float* __restrict__ xres,
                                                    float* __restrict__ out) {
    // A halo tile: 136 tokens x 32 k = 68 lines x 128B ; B: 3 taps x 128 x 32
    __shared__ __align__(16) bf16 As[2][136 * 32];
    __shared__ __align__(16) bf16 Bs[2][3 * 4096];

    int tid = threadIdx.x;
    int wave = tid >> 6, lane = tid & 63;
    int l15 = lane & 15, quad = lane >> 4;
    int wm = wave >> 1, wn = wave & 1;
    int m0 = blockIdx.y * 128, n0 = blockIdx.x * 128;
    int b = m0 >> 10, oh0 = (m0 & 1023) >> 5;      // block = 4 image rows of one batch

    // ---- A staging: swizzle-decoded per-lane source (linear LDS dest) ----
    int rA1, cA1, rA2, cA2, rA3, cA3;
    swz_decode(tid,              rA1, cA1);
    swz_decode(tid + 256,        rA2, cA2);
    swz_decode((tid & 31) + 512, rA3, cA3);        // only staged when tid<32
    int rr1 = rA1 / 34, co1 = rA1 - rr1 * 34;
    int rr2 = rA2 / 34, co2 = rA2 - rr2 * 34;
    int rr3 = rA3 / 34, co3 = rA3 - rr3 * 34;
    const size_t dyStride = (size_t)PROW * Cc;
    const bf16* pA1 = Pad + ((size_t)b * PIMG + (size_t)(oh0 + rr1) * PROW + co1) * Cc + cA1 * 8;
    const bf16* pA2 = Pad + ((size_t)b * PIMG + (size_t)(oh0 + rr2) * PROW + co2) * Cc + cA2 * 8;
    const bf16* pA3 = Pad + ((size_t)b * PIMG + (size_t)(oh0 + rr3) * PROW + co3) * Cc + cA3 * 8;

    // ---- B staging: swizzle-decoded per-lane source ----
    int rB1, cB1, rB2, cB2;
    swz_decode(wave * 128 + lane,      rB1, cB1);
    swz_decode(wave * 128 + 64 + lane, rB2, cB2);
    const bf16* gw1 = Wct + (size_t)(n0 + rB1) * Cc + cB1 * 8;
    const bf16* gw2 = Wct + (size_t)(n0 + rB2) * Cc + cB2 * 8;

    // ---- precomputed swizzled read offsets (bf16 elems) ----
    int aoff[3][4], boff[4];
#pragma unroll
    for (int mt = 0; mt < 4; mt++) {
        int rbase = (wm * 2 + (mt >> 1)) * 34 + (mt & 1) * 16 + l15;
#pragma unroll
        for (int dxi = 0; dxi < 3; dxi++) aoff[dxi][mt] = swz_off(rbase + dxi, quad);
    }
#pragma unroll
    for (int nt = 0; nt < 4; nt++) boff[nt] = swz_off(wn * 64 + nt * 16 + l15, quad);

    // stage iteration 'it' (dyi = it>>4, k0 = (it&15)*32) into buffer p
    // wave0 issues 9 vmem ops, waves1-3 issue 8 -> uniform vmcnt(8) is safe
    auto stage_it = [&](int it, int p) {
        int dyi = it >> 4;
        int k0 = (it & 15) << 5;
        size_t ag = (size_t)dyi * dyStride + k0;
        stage16(pA1 + ag, &As[p][wave * 512]);
        stage16(pA2 + ag, &As[p][2048 + wave * 512]);
        if (tid < 32) stage16(pA3 + ag, &As[p][4096]);
        size_t wg = (size_t)(dyi * 3) * (Cc * Cc) + k0;
#pragma unroll
        for (int t = 0; t < 3; t++) {
            size_t tg = wg + (size_t)t * (Cc * Cc);
            stage16(gw1 + tg, &Bs[p][t * 4096 + wave * 1024]);
            stage16(gw2 + tg, &Bs[p][t * 4096 + wave * 1024 + 512]);
        }
    };

    f32x4 acc[4][4] = {};
    stage_it(0, 0);
    for (int it = 0; it < 48; ++it) {
        int p = it & 1;
        if (it + 1 < 48) {
            stage_it(it + 1, p ^ 1);
            asm volatile("s_waitcnt vmcnt(8)" ::: "memory");   // this tile landed; next stays in flight
        } else {
            asm volatile("s_waitcnt vmcnt(0)" ::: "memory");
        }
        __builtin_amdgcn_s_barrier();                          // all waves: buf[p] staged
        __builtin_amdgcn_sched_barrier(0);

        short8 af[3][4], bfv[3][4];
        // ---- issue dxi0 + dxi1 reads ----
#pragma unroll
        for (int dxi = 0; dxi < 2; dxi++) {
#pragma unroll
            for (int mt = 0; mt < 4; mt++)
                af[dxi][mt] = *(const short8*)&As[p][aoff[dxi][mt]];
#pragma unroll
            for (int nt = 0; nt < 4; nt++)
                bfv[dxi][nt] = *(const short8*)&Bs[p][dxi * 4096 + boff[nt]];
        }
        __builtin_amdgcn_sched_barrier(0);
        // ---- MFMA dxi0 (compiler inserts counted lgkm wait for its 8 reads) ----
        __builtin_amdgcn_s_setprio(1);
#pragma unroll
        for (int mt = 0; mt < 4; mt++)
#pragma unroll
            for (int nt = 0; nt < 4; nt++)
                acc[mt][nt] = __builtin_amdgcn_mfma_f32_16x16x32_bf16(af[0][mt], bfv[0][nt], acc[mt][nt], 0, 0, 0);
        __builtin_amdgcn_s_setprio(0);
        __builtin_amdgcn_sched_barrier(0);
        // ---- issue dxi2 reads (overlap with dxi0 MFMA above / dxi1 below) ----
#pragma unroll
        for (int mt = 0; mt < 4; mt++)
            af[2][mt] = *(const short8*)&As[p][aoff[2][mt]];
#pragma unroll
        for (int nt = 0; nt < 4; nt++)
            bfv[2][nt] = *(const short8*)&Bs[p][2 * 4096 + boff[nt]];
        __builtin_amdgcn_sched_barrier(0);
        // ---- MFMA dxi1 ----
        __builtin_amdgcn_s_setprio(1);
#pragma unroll
        for (int mt = 0; mt < 4; mt++)
#pragma unroll
            for (int nt = 0; nt < 4; nt++)
                acc[mt][nt] = __builtin_amdgcn_mfma_f32_16x16x32_bf16(af[1][mt], bfv[1][nt], acc[mt][nt], 0, 0, 0);
        __builtin_amdgcn_s_setprio(0);
        __builtin_amdgcn_sched_barrier(0);
        // ---- all reads of buf[p] done -> read-done barrier; dxi2 MFMA after,
        //      overlapping other waves' next-tile stage issue ----
        asm volatile("s_waitcnt lgkmcnt(0)" ::: "memory");
        __builtin_amdgcn_sched_barrier(0);
        __builtin_amdgcn_s_barrier();
        __builtin_amdgcn_s_setprio(1);
#pragma unroll
        for (int mt = 0; mt < 4; mt++)
#pragma unroll
            for (int nt = 0; nt < 4; nt++)
                acc[mt][nt] = __builtin_amdgcn_mfma_f32_16x16x32_bf16(af[2][mt], bfv[2][nt], acc[mt][nt], 0, 0, 0);
        __builtin_amdgcn_s_setprio(0);
    }

#pragma unroll
    for (int mt = 0; mt < 4; mt++)
#pragma unroll
        for (int r = 0; r < 4; r++) {
            size_t row = (size_t)(m0 + wm * 64 + mt * 16 + quad * 4 + r) * Cc + n0 + wn * 64 + l15;
#pragma unroll
            for (int nt = 0; nt < 4; nt++) {
                int n = n0 + wn * 64 + nt * 16 + l15;
                out[row + nt * 16] = acc[mt][nt][r] + bias[n] + xres[row + nt * 16];
            }
        }
}

// ---------------------------------------------------------------------------
extern "C" void kernel_launch(void* const* d_in, const int* in_sizes, int n_in,
                              void* d_out, int out_size, void* d_ws, size_t ws_size,
                              hipStream_t stream) {
    const float* x     = (const float*)d_in[0];
    const float* gamma = (const float*)d_in[1];
    const float* beta  = (const float*)d_in[2];
    const float* wq    = (const float*)d_in[3];
    const float* wk    = (const float*)d_in[4];
    const float* wv    = (const float*)d_in[5];
    const float* convw = (const float*)d_in[6];
    const float* convb = (const float*)d_in[7];
    float* out = (float*)d_out;

    // ws layout (time-multiplexed; peak ~71.5 MiB):
    //   [0, 18.9 MiB)  : pad   (written by zero_pad+attention AFTER gemm_qkv)
    //   [0, 4 KiB)     : stats (dead before pad is written)
    //   [4 KiB, +16MiB): xn    (dead before pad is written)
    //   [xn end, +1.5M): wt    (dead before pad is written)
    //   [19 MiB, +32M) : qk    (Q,K rows, stride 1024)
    //   [51 MiB, +16M) : vT    (V transposed [h][d][b*1024+tok])
    //   [67 MiB, +4.5M): wct
    char* ws = (char*)d_ws;
    bf16*  pad   = (bf16*)ws;
    float* stats = (float*)ws;
    bf16*  xn    = (bf16*)(ws + 4096);
    bf16*  wt    = (bf16*)(ws + 4096 + ((size_t)16 << 20));
    bf16*  qk    = (bf16*)(ws + ((size_t)19 << 20));
    bf16*  vt    = (bf16*)(ws + ((size_t)51 << 20));
    bf16*  wct   = (bf16*)(ws + ((size_t)67 << 20));

    // weight prep (dst regions distinct from src-time-live data)
    wtrans<<<dim3(128, 1), 256, 0, stream>>>(wq, wt);
    wtrans<<<dim3(128, 1), 256, 0, stream>>>(wk, wt + 262144);
    wtrans<<<dim3(128, 1), 256, 0, stream>>>(wv, wt + 524288);
    wtrans<<<dim3(128, 9), 256, 0, stream>>>(convw, wct);

    gn_stats<<<dim3(Bn * GROUPS), 256, 0, stream>>>(x, stats);
    gn_apply<<<dim3(Mtok * Cc / (4 * 256)), 256, 0, stream>>>(x, stats, gamma, beta, xn);

    gemm_qkv<<<dim3(QKVS / 128, Mtok / 128), 256, 0, stream>>>(xn, wt, qk, vt);

    zero_pad<<<dim3(528), 256, 0, stream>>>(pad);   // after gemm_qkv: region overlaps xn/wt
    attention_mfma<<<dim3(Bn * HEADS * (Ss / 128)), 256, 0, stream>>>(qk, vt, pad);

    conv_mfma<<<dim3(Cc / 128, Mtok / 128), 256, 0, stream>>>(pad, wct, convb, x, out);
}

// Round 8
// 311.522 us; speedup vs baseline: 1.0239x; 1.0089x over previous
//
#include <hip/hip_runtime.h>
#include <hip/hip_bf16.h>

// Problem constants
#define Bn 16
#define Cc 512
#define Ss 1024           // H*W tokens per batch
#define HEADS 8
#define DHEAD 64
#define GROUPS 32
#define CPG 16
#define EPSv 1e-5f
#define Mtok (Bn*Ss)      // 16384 token rows
#define QKVS 1536         // (legacy) fused qkv row stride
#define QKS 1024          // Q+K row stride (V split out transposed)
#define PROW 34           // padded image row (32 + halo)
#define PIMG (PROW*PROW)  // 1156 padded tokens per batch

typedef __hip_bfloat16 bf16;
typedef __attribute__((ext_vector_type(8))) short short8;   // MFMA A/B frag (8 bf16)
typedef __attribute__((ext_vector_type(4))) float f32x4;    // MFMA C/D frag

union U4 { uint4 u; bf16 h[8]; };
union B4 { ushort4 u; bf16 h[4]; };

// async global->LDS, 16 B/lane; LDS dest = wave-uniform base + lane*16
__device__ __forceinline__ void stage16(const bf16* g, bf16* l) {
    __builtin_amdgcn_global_load_lds((const __attribute__((address_space(1))) void*)g,
                                     (__attribute__((address_space(3))) void*)l,
                                     16, 0, 0);
}

// pack two f32 -> one dword of 2 bf16 (lo=a, hi=b)
__device__ __forceinline__ unsigned int pkbf(float a, float b) {
    union { __hip_bfloat16 h; unsigned short u; } ua, ub;
    ua.h = __float2bfloat16(a); ub.h = __float2bfloat16(b);
    return ((unsigned int)ub.u << 16) | ua.u;
}

// ---- T2 pair-row XOR swizzle (128-B lines of 8 x 16-B chunks) ----
// logical (row r, chunk c) stored at line=r>>1, pos=((r&1)*4+c)^(line&7)
__device__ __forceinline__ void swz_decode(int F, int& r, int& c) {
    int line = F >> 3, pos = F & 7;
    int u = pos ^ (line & 7);
    r = (line << 1) | (u >> 2);
    c = u & 3;
}
// read offset in bf16 elems for logical (r, chunk q)
__device__ __forceinline__ int swz_off(int r, int q) {
    return (r >> 1) * 64 + (((((r & 1) << 2) + q) ^ ((r >> 1) & 7)) << 3);
}

// ---------------------------------------------------------------------------
// 0) Weight transpose+convert: src f32 [512][512] (k-major) -> dst bf16 [n][k]
//    wtrans3 = q,k,v fused into one launch (blockIdx.y selects source)
// ---------------------------------------------------------------------------
__global__ __launch_bounds__(256) void wtrans3(const float* __restrict__ wq,
                                               const float* __restrict__ wk,
                                               const float* __restrict__ wv,
                                               bf16* __restrict__ dst) {
    const float* src = (blockIdx.y == 0) ? wq : (blockIdx.y == 1) ? wk : wv;
    size_t off = (size_t)blockIdx.y * 262144;
    int t = blockIdx.x * 256 + threadIdx.x;     // 0..32767
    int n = t & 511, k8 = (t >> 9) * 8;
    const float* s = src + (size_t)k8 * 512 + n;
    U4 o;
#pragma unroll
    for (int j = 0; j < 8; j++) o.h[j] = __float2bfloat16(s[(size_t)j * 512]);
    *(uint4*)(dst + off + (size_t)n * 512 + k8) = o.u;
}

__global__ __launch_bounds__(256) void wtrans(const float* __restrict__ src,
                                              bf16* __restrict__ dst) {
    size_t off = (size_t)blockIdx.y * 262144;
    int t = blockIdx.x * 256 + threadIdx.x;     // 0..32767
    int n = t & 511, k8 = (t >> 9) * 8;
    const float* s = src + off + (size_t)k8 * 512 + n;
    U4 o;
#pragma unroll
    for (int j = 0; j < 8; j++) o.h[j] = __float2bfloat16(s[(size_t)j * 512]);
    *(uint4*)(dst + off + (size_t)n * 512 + k8) = o.u;
}

// ---------------------------------------------------------------------------
// 1) GroupNorm stats
// ---------------------------------------------------------------------------
__global__ __launch_bounds__(256) void gn_stats(const float* __restrict__ x,
                                                float* __restrict__ stats) {
    int bg = blockIdx.x;
    int b = bg >> 5, g = bg & 31;
    int tid = threadIdx.x;
    const size_t base = (size_t)b * Ss * Cc + g * CPG;
    float sum = 0.f, sq = 0.f;
    for (int i = tid; i < 4096; i += 256) {
        int s = i >> 2, c4 = (i & 3) * 4;
        float4 t = *(const float4*)(x + base + (size_t)s * Cc + c4);
        sum += t.x + t.y + t.z + t.w;
        sq  += t.x * t.x + t.y * t.y + t.z * t.z + t.w * t.w;
    }
    __shared__ float s1[4], s2[4];
#pragma unroll
    for (int off = 32; off > 0; off >>= 1) {
        sum += __shfl_down(sum, off);
        sq  += __shfl_down(sq,  off);
    }
    if ((tid & 63) == 0) { s1[tid >> 6] = sum; s2[tid >> 6] = sq; }
    __syncthreads();
    if (tid == 0) {
        float S = s1[0] + s1[1] + s1[2] + s1[3];
        float Q = s2[0] + s2[1] + s2[2] + s2[3];
        float mean = S * (1.f / 16384.f);
        float var  = Q * (1.f / 16384.f) - mean * mean;
        stats[bg * 2 + 0] = mean;
        stats[bg * 2 + 1] = rsqrtf(var + EPSv);
    }
}

// ---------------------------------------------------------------------------
// 2) GroupNorm apply (f32 in, bf16 out)
// ---------------------------------------------------------------------------
__global__ __launch_bounds__(256) void gn_apply(const float* __restrict__ x,
                                                const float* __restrict__ stats,
                                                const float* __restrict__ gamma,
                                                const float* __restrict__ beta,
                                                bf16* __restrict__ xn) {
    size_t i = (size_t)blockIdx.x * 256 + threadIdx.x;
    size_t e = i * 4;
    int c0 = (int)(e & (Cc - 1));
    int token = (int)(e >> 9);
    int b = token >> 10;
    int g = c0 >> 4;
    float mean = stats[(b * 32 + g) * 2 + 0];
    float rstd = stats[(b * 32 + g) * 2 + 1];
    float4 t  = *(const float4*)(x + e);
    float4 gm = *(const float4*)(gamma + c0);
    float4 bt = *(const float4*)(beta + c0);
    B4 o;
    o.h[0] = __float2bfloat16((t.x - mean) * rstd * gm.x + bt.x);
    o.h[1] = __float2bfloat16((t.y - mean) * rstd * gm.y + bt.y);
    o.h[2] = __float2bfloat16((t.z - mean) * rstd * gm.z + bt.z);
    o.h[3] = __float2bfloat16((t.w - mean) * rstd * gm.w + bt.w);
    *(ushort4*)(xn + e) = o.u;
}

// ---------------------------------------------------------------------------
// 2b) Zero the padded-activation border (132 border tokens x 512 ch x 16 b)
// ---------------------------------------------------------------------------
__global__ __launch_bounds__(256) void zero_pad(bf16* __restrict__ Pad) {
    int idx = blockIdx.x * 256 + threadIdx.x;     // exactly 16*132*64
    int b = idx / (132 * 64);
    int rem = idx - b * 132 * 64;
    int t = rem >> 6, seg = rem & 63;
    int r, c;
    if (t < 34)      { r = 0;  c = t; }
    else if (t < 68) { r = 33; c = t - 34; }
    else { int u = t - 68; r = 1 + (u >> 1); c = (u & 1) * 33; }
    uint4 z = {0u, 0u, 0u, 0u};
    *(uint4*)(Pad + ((size_t)b * PIMG + r * PROW + c) * Cc + seg * 8) = z;
}

// ---------------------------------------------------------------------------
// 3) Fused QKV GEMM: 128x128 tile + 2-phase counted-vmcnt double-buffer
//    + T2 pair-row swizzle (linear LDS dest, swz source, swz read).
//    Q,K -> QK buffer (row stride 1024); V -> transposed vT[h][d][b*1024+tok].
// ---------------------------------------------------------------------------
__global__ __launch_bounds__(256) void gemm_qkv(const bf16* __restrict__ A,
                                                const bf16* __restrict__ Wt,
                                                bf16* __restrict__ C,
                                                bf16* __restrict__ vT) {
    __shared__ __align__(16) bf16 As[2][4096];
    __shared__ __align__(16) bf16 Bs[2][4096];
    int tid = threadIdx.x;
    int wave = tid >> 6, lane = tid & 63;
    int l15 = lane & 15, quad = lane >> 4;
    int wm = wave >> 1, wn = wave & 1;
    int m0 = blockIdx.y * 128, n0 = blockIdx.x * 128;

    // swizzle-decoded per-lane staging sources: wave handles segments 2w,2w+1
    int r0_, c0_, r1_, c1_;
    swz_decode(wave * 128 + lane,      r0_, c0_);
    swz_decode(wave * 128 + 64 + lane, r1_, c1_);
    const bf16* gaS0 = A  + (size_t)(m0 + r0_) * Cc + c0_ * 8;
    const bf16* gaS1 = A  + (size_t)(m0 + r1_) * Cc + c1_ * 8;
    const bf16* gbS0 = Wt + (size_t)(n0 + r0_) * Cc + c0_ * 8;
    const bf16* gbS1 = Wt + (size_t)(n0 + r1_) * Cc + c1_ * 8;

    int aoffg[4], boffg[4];
#pragma unroll
    for (int mt = 0; mt < 4; mt++) aoffg[mt] = swz_off(wm * 64 + mt * 16 + l15, quad);
#pragma unroll
    for (int nt = 0; nt < 4; nt++) boffg[nt] = swz_off(wn * 64 + nt * 16 + l15, quad);

    // each wave stages 4 segments/tile -> vmcnt(4) == current tile landed
    auto stageg = [&](int k0, int p) {
        stage16(gaS0 + k0, &As[p][wave * 1024]);
        stage16(gaS1 + k0, &As[p][wave * 1024 + 512]);
        stage16(gbS0 + k0, &Bs[p][wave * 1024]);
        stage16(gbS1 + k0, &Bs[p][wave * 1024 + 512]);
    };

    f32x4 acc[4][4] = {};
    stageg(0, 0);
    for (int it = 0; it < 16; ++it) {
        int p = it & 1;
        if (it + 1 < 16) {
            stageg((it + 1) * 32, p ^ 1);
            asm volatile("s_waitcnt vmcnt(4)" ::: "memory");   // this tile landed; next in flight
        } else {
            asm volatile("s_waitcnt vmcnt(0)" ::: "memory");
        }
        __builtin_amdgcn_s_barrier();                          // BAR_A: buf[p] staged
        __builtin_amdgcn_sched_barrier(0);                     // keep reads below BAR_A

        short8 af[4], bfv[4];
        af[0] = *(const short8*)&As[p][aoffg[0]];
#pragma unroll
        for (int nt = 0; nt < 4; nt++) bfv[nt] = *(const short8*)&Bs[p][boffg[nt]];
#pragma unroll
        for (int mt = 1; mt < 4; mt++) af[mt] = *(const short8*)&As[p][aoffg[mt]];

        __builtin_amdgcn_s_setprio(1);
#pragma unroll
        for (int mt = 0; mt < 3; mt++)
#pragma unroll
            for (int nt = 0; nt < 4; nt++)
                acc[mt][nt] = __builtin_amdgcn_mfma_f32_16x16x32_bf16(af[mt], bfv[nt], acc[mt][nt], 0, 0, 0);
        __builtin_amdgcn_s_setprio(0);
        asm volatile("s_waitcnt lgkmcnt(0)" ::: "memory");     // all buf[p] reads done
        __builtin_amdgcn_s_barrier();                          // BAR_B: buf[p] free
        __builtin_amdgcn_s_setprio(1);
#pragma unroll
        for (int nt = 0; nt < 4; nt++)
            acc[3][nt] = __builtin_amdgcn_mfma_f32_16x16x32_bf16(af[3], bfv[nt], acc[3][nt], 0, 0, 0);
        __builtin_amdgcn_s_setprio(0);
    }

    if (n0 < 1024) {
        // Q/K: normal store, row stride QKS
#pragma unroll
        for (int mt = 0; mt < 4; mt++)
#pragma unroll
            for (int r = 0; r < 4; r++) {
                size_t row = (size_t)(m0 + wm * 64 + mt * 16 + quad * 4 + r) * QKS + n0 + wn * 64 + l15;
#pragma unroll
                for (int nt = 0; nt < 4; nt++)
                    C[row + nt * 16] = __float2bfloat16(acc[mt][nt][r]);
            }
    } else {
        // V: transposed store vT[(h*64+d)][b*1024 + tok], 8B packed along tok
        int hh = ((n0 - 1024) >> 6) + wn;          // head
        int bq = m0 >> 10;
        int tok0 = (m0 & 1023) + wm * 64;
#pragma unroll
        for (int nt = 0; nt < 4; nt++) {
            int d = nt * 16 + l15;
            bf16* drow = vT + (size_t)(hh * 64 + d) * 16384 + bq * 1024 + tok0;
#pragma unroll
            for (int mt = 0; mt < 4; mt++) {
                B4 o;
#pragma unroll
                for (int r = 0; r < 4; r++) o.h[r] = __float2bfloat16(acc[mt][nt][r]);
                *(ushort4*)(drow + mt * 16 + quad * 4) = o.u;
            }
        }
    }
}

// ---------------------------------------------------------------------------
// 4) Flash-style MFMA attention, KVBLK=64, 2-phase counted-vmcnt dbuf,
//    Q-blocked (32 q-rows/wave). Unchanged from round 6 (verified twice).
// ---------------------------------------------------------------------------
__global__ __launch_bounds__(256) void attention_mfma(const bf16* __restrict__ QK,
                                                      const bf16* __restrict__ vT,
                                                      bf16* __restrict__ Pad) {
    int blk = blockIdx.x;
    int qt = blk & 7;                 // 8 q-blocks of 128 per (b,h)
    int bh = blk >> 3;
    int h = bh & (HEADS - 1), b = bh >> 3;
    int tid = threadIdx.x;
    int wave = tid >> 6, lane = tid & 63;
    int l15 = lane & 15, quad = lane >> 4;

    // K tile: 64 toks x 64 ch (rows 128B, swizzled); V^T tile: 64 d x 64 toks
    __shared__ __align__(16) bf16 KT[2][4096];
    __shared__ __align__(16) bf16 VTs[2][4096];

    const size_t base = (size_t)b * Ss * QKS + h * DHEAD;
    const bf16* kbase = QK + base + 512;

    int q0 = qt * 128 + wave * 32;    // wave's 32 q-rows (2 sub-blocks of 16)
    const bf16* qrow = QK + base + (size_t)(q0 + l15) * QKS + quad * 8;
    short8 qfA0 = *(const short8*)(qrow);
    short8 qfA1 = *(const short8*)(qrow + 32);
    short8 qfB0 = *(const short8*)(qrow + 16 * QKS);
    short8 qfB1 = *(const short8*)(qrow + 16 * QKS + 32);

    // staging geometry: chunks c=tid (rows 0..31) and c=tid+256 (rows 32..63)
    // chunk c -> (row=c>>3, col16=c&7); source col16 pre-swizzled ^ (row&7)
    int r1 = tid >> 3,         f1 = (tid & 7) ^ (r1 & 7);
    int r2 = (tid + 256) >> 3, f2 = ((tid + 256) & 7) ^ (r2 & 7);
    const bf16* gk1 = kbase + (size_t)r1 * QKS + f1 * 8;
    const bf16* gk2 = kbase + (size_t)r2 * QKS + f2 * 8;
    const bf16* gv1 = vT + (size_t)(h * 64 + r1) * 16384 + b * 1024 + f1 * 8;
    const bf16* gv2 = vT + (size_t)(h * 64 + r2) * 16384 + b * 1024 + f2 * 8;

    f32x4 oacc0[4] = {{0.f,0.f,0.f,0.f},{0.f,0.f,0.f,0.f},{0.f,0.f,0.f,0.f},{0.f,0.f,0.f,0.f}};
    f32x4 oacc1[4] = {{0.f,0.f,0.f,0.f},{0.f,0.f,0.f,0.f},{0.f,0.f,0.f,0.f},{0.f,0.f,0.f,0.f}};
    float lsum0 = 0.f, lsum1 = 0.f;
    const f32x4 zero4 = {0.f, 0.f, 0.f, 0.f};
    int srcA = ((quad & 1) * 2) * 16 + l15;   // P^T exchange source lanes
    int srcB = srcA + 16;
    bool hiq = (quad >= 2);
    int sw = l15 & 7;                          // read-side swizzle key

    auto stage = [&](int c0, int p) {
        stage16(gk1 + (size_t)c0 * QKS, &KT[p][wave * 512]);
        stage16(gk2 + (size_t)c0 * QKS, &KT[p][2048 + wave * 512]);
        stage16(gv1 + c0,               &VTs[p][wave * 512]);
        stage16(gv2 + c0,               &VTs[p][2048 + wave * 512]);
    };

    stage(0, 0);
    for (int it = 0; it < 16; ++it) {
        int p = it & 1;
        if (it + 1 < 16) {
            stage((it + 1) * 64, p ^ 1);
            asm volatile("s_waitcnt vmcnt(4)" ::: "memory");  // buf p landed; next in flight
        } else {
            asm volatile("s_waitcnt vmcnt(0)" ::: "memory");
        }
        __builtin_amdgcn_s_barrier();
        __builtin_amdgcn_sched_barrier(0);

        // ---- swapped QK^T over 64 toks x 32 q: K-frags read ONCE, used for
        //      both q sub-blocks. Lane holds S^T[t=kb*16+quad*4+r][q=l15].
        unsigned int pk0[4][2], pk1[4][2];
        __builtin_amdgcn_s_setprio(1);
#pragma unroll
        for (int kb = 0; kb < 4; kb++) {
            const bf16* kr = &KT[p][(kb * 16 + l15) * 64];
            short8 kf0 = *(const short8*)(kr + ((quad ^ sw) * 8));
            short8 kf1 = *(const short8*)(kr + (((4 + quad) ^ sw) * 8));
            f32x4 s0 = __builtin_amdgcn_mfma_f32_16x16x32_bf16(kf0, qfA0, zero4, 0, 0, 0);
            s0 = __builtin_amdgcn_mfma_f32_16x16x32_bf16(kf1, qfA1, s0, 0, 0, 0);
            f32x4 s1 = __builtin_amdgcn_mfma_f32_16x16x32_bf16(kf0, qfB0, zero4, 0, 0, 0);
            s1 = __builtin_amdgcn_mfma_f32_16x16x32_bf16(kf1, qfB1, s1, 0, 0, 0);
            float a0 = __expf(s0[0] * 0.125f);
            float a1 = __expf(s0[1] * 0.125f);
            float a2 = __expf(s0[2] * 0.125f);
            float a3 = __expf(s0[3] * 0.125f);
            lsum0 += (a0 + a1) + (a2 + a3);
            pk0[kb][0] = pkbf(a0, a1);
            pk0[kb][1] = pkbf(a2, a3);
            float b0 = __expf(s1[0] * 0.125f);
            float b1 = __expf(s1[1] * 0.125f);
            float b2 = __expf(s1[2] * 0.125f);
            float b3 = __expf(s1[3] * 0.125f);
            lsum1 += (b0 + b1) + (b2 + b3);
            pk1[kb][0] = pkbf(b0, b1);
            pk1[kb][1] = pkbf(b2, b3);
        }
        __builtin_amdgcn_s_setprio(0);

        // ---- quad exchange per q sub-block: P^T B-frags for t halves
        union { short8 s8; unsigned int u[4]; } PT00, PT01, PT10, PT11;
        {
            unsigned int A0 = __shfl((int)pk0[0][0], srcA), A1 = __shfl((int)pk0[0][1], srcA);
            unsigned int A2 = __shfl((int)pk0[1][0], srcA), A3 = __shfl((int)pk0[1][1], srcA);
            unsigned int B0 = __shfl((int)pk0[0][0], srcB), B1 = __shfl((int)pk0[0][1], srcB);
            unsigned int B2 = __shfl((int)pk0[1][0], srcB), B3 = __shfl((int)pk0[1][1], srcB);
            PT00.u[0] = hiq ? A2 : A0;  PT00.u[1] = hiq ? A3 : A1;
            PT00.u[2] = hiq ? B2 : B0;  PT00.u[3] = hiq ? B3 : B1;
            unsigned int C0 = __shfl((int)pk0[2][0], srcA), C1 = __shfl((int)pk0[2][1], srcA);
            unsigned int C2 = __shfl((int)pk0[3][0], srcA), C3 = __shfl((int)pk0[3][1], srcA);
            unsigned int D0 = __shfl((int)pk0[2][0], srcB), D1 = __shfl((int)pk0[2][1], srcB);
            unsigned int D2 = __shfl((int)pk0[3][0], srcB), D3 = __shfl((int)pk0[3][1], srcB);
            PT01.u[0] = hiq ? C2 : C0;  PT01.u[1] = hiq ? C3 : C1;
            PT01.u[2] = hiq ? D2 : D0;  PT01.u[3] = hiq ? D3 : D1;
        }
        {
            unsigned int A0 = __shfl((int)pk1[0][0], srcA), A1 = __shfl((int)pk1[0][1], srcA);
            unsigned int A2 = __shfl((int)pk1[1][0], srcA), A3 = __shfl((int)pk1[1][1], srcA);
            unsigned int B0 = __shfl((int)pk1[0][0], srcB), B1 = __shfl((int)pk1[0][1], srcB);
            unsigned int B2 = __shfl((int)pk1[1][0], srcB), B3 = __shfl((int)pk1[1][1], srcB);
            PT10.u[0] = hiq ? A2 : A0;  PT10.u[1] = hiq ? A3 : A1;
            PT10.u[2] = hiq ? B2 : B0;  PT10.u[3] = hiq ? B3 : B1;
            unsigned int C0 = __shfl((int)pk1[2][0], srcA), C1 = __shfl((int)pk1[2][1], srcA);
            unsigned int C2 = __shfl((int)pk1[3][0], srcA), C3 = __shfl((int)pk1[3][1], srcA);
            unsigned int D0 = __shfl((int)pk1[2][0], srcB), D1 = __shfl((int)pk1[2][1], srcB);
            unsigned int D2 = __shfl((int)pk1[3][0], srcB), D3 = __shfl((int)pk1[3][1], srcB);
            PT11.u[0] = hiq ? C2 : C0;  PT11.u[1] = hiq ? C3 : C1;
            PT11.u[2] = hiq ? D2 : D0;  PT11.u[3] = hiq ? D3 : D1;
        }

        // ---- PV: O^T += V^T . P^T — V-frags read ONCE, used for both q-blocks
        __builtin_amdgcn_s_setprio(1);
#pragma unroll
        for (int dt = 0; dt < 4; dt++) {
            const bf16* vr = &VTs[p][(dt * 16 + l15) * 64];
            short8 vf0 = *(const short8*)(vr + ((quad ^ sw) * 8));
            short8 vf1 = *(const short8*)(vr + (((4 + quad) ^ sw) * 8));
            oacc0[dt] = __builtin_amdgcn_mfma_f32_16x16x32_bf16(vf0, PT00.s8, oacc0[dt], 0, 0, 0);
            oacc0[dt] = __builtin_amdgcn_mfma_f32_16x16x32_bf16(vf1, PT01.s8, oacc0[dt], 0, 0, 0);
            oacc1[dt] = __builtin_amdgcn_mfma_f32_16x16x32_bf16(vf0, PT10.s8, oacc1[dt], 0, 0, 0);
            oacc1[dt] = __builtin_amdgcn_mfma_f32_16x16x32_bf16(vf1, PT11.s8, oacc1[dt], 0, 0, 0);
        }
        __builtin_amdgcn_s_setprio(0);

        __builtin_amdgcn_sched_barrier(0);   // pin reads above read-done barrier
        __builtin_amdgcn_s_barrier();        // read-done: next iter may overwrite buf p
        __builtin_amdgcn_sched_barrier(0);   // pin next stage below
    }

    // denoms for q=l15 of each sub-block: sum partials across the 4 quads
    lsum0 += __shfl_xor(lsum0, 16);
    lsum0 += __shfl_xor(lsum0, 32);
    lsum1 += __shfl_xor(lsum1, 16);
    lsum1 += __shfl_xor(lsum1, 32);
    float inv0 = 1.f / lsum0;
    float inv1 = 1.f / lsum1;

    {
        int s = q0 + l15;
        size_t rowoff = ((size_t)(b * PROW + (s >> 5) + 1) * PROW + (s & 31) + 1) * Cc + h * DHEAD;
#pragma unroll
        for (int dt = 0; dt < 4; dt++) {
            B4 o;
#pragma unroll
            for (int r = 0; r < 4; r++) o.h[r] = __float2bfloat16(oacc0[dt][r] * inv0);
            *(ushort4*)(Pad + rowoff + dt * 16 + quad * 4) = o.u;
        }
    }
    {
        int s = q0 + 16 + l15;
        size_t rowoff = ((size_t)(b * PROW + (s >> 5) + 1) * PROW + (s & 31) + 1) * Cc + h * DHEAD;
#pragma unroll
        for (int dt = 0; dt < 4; dt++) {
            B4 o;
#pragma unroll
            for (int r = 0; r < 4; r++) o.h[r] = __float2bfloat16(oacc1[dt][r] * inv1);
            *(ushort4*)(Pad + rowoff + dt * 16 + quad * 4) = o.u;
        }
    }
}

// ---------------------------------------------------------------------------
// 5) 3x3 conv as implicit GEMM, dx-tap sharing + 2-phase counted-vmcnt dbuf
//    + T2 swizzle. MINIMAL FENCES: all 24 reads issued up front (dxi-ordered),
//    MFMA(dxi0,1) overlap the later reads via compiler counted-lgkm waits
//    (DS returns in-order); lgkmcnt(0) pins reads above the read-done
//    barrier; MFMA(dxi2) slides past it to overlap other waves' staging.
// ---------------------------------------------------------------------------
__global__ __launch_bounds__(256, 2) void conv_mfma(const bf16* __restrict__ Pad,
                                                    const bf16* __restrict__ Wct,
                                                    const float* __restrict__ bias,
                                                    const float* __restrict__ xres,
                                                    float* __restrict__ out) {
    // A halo tile: 136 tokens x 32 k = 68 lines x 128B ; B: 3 taps x 128 x 32
    __shared__ __align__(16) bf16 As[2][136 * 32];
    __shared__ __align__(16) bf16 Bs[2][3 * 4096];

    int tid = threadIdx.x;
    int wave = tid >> 6, lane = tid & 63;
    int l15 = lane & 15, quad = lane >> 4;
    int wm = wave >> 1, wn = wave & 1;
    int m0 = blockIdx.y * 128, n0 = blockIdx.x * 128;
    int b = m0 >> 10, oh0 = (m0 & 1023) >> 5;      // block = 4 image rows of one batch

    // ---- A staging: swizzle-decoded per-lane source (linear LDS dest) ----
    int rA1, cA1, rA2, cA2, rA3, cA3;
    swz_decode(tid,              rA1, cA1);
    swz_decode(tid + 256,        rA2, cA2);
    swz_decode((tid & 31) + 512, rA3, cA3);        // only staged when tid<32
    int rr1 = rA1 / 34, co1 = rA1 - rr1 * 34;
    int rr2 = rA2 / 34, co2 = rA2 - rr2 * 34;
    int rr3 = rA3 / 34, co3 = rA3 - rr3 * 34;
    const size_t dyStride = (size_t)PROW * Cc;
    const bf16* pA1 = Pad + ((size_t)b * PIMG + (size_t)(oh0 + rr1) * PROW + co1) * Cc + cA1 * 8;
    const bf16* pA2 = Pad + ((size_t)b * PIMG + (size_t)(oh0 + rr2) * PROW + co2) * Cc + cA2 * 8;
    const bf16* pA3 = Pad + ((size_t)b * PIMG + (size_t)(oh0 + rr3) * PROW + co3) * Cc + cA3 * 8;

    // ---- B staging: swizzle-decoded per-lane source ----
    int rB1, cB1, rB2, cB2;
    swz_decode(wave * 128 + lane,      rB1, cB1);
    swz_decode(wave * 128 + 64 + lane, rB2, cB2);
    const bf16* gw1 = Wct + (size_t)(n0 + rB1) * Cc + cB1 * 8;
    const bf16* gw2 = Wct + (size_t)(n0 + rB2) * Cc + cB2 * 8;

    // ---- precomputed swizzled read offsets (bf16 elems) ----
    int aoff[3][4], boff[4];
#pragma unroll
    for (int mt = 0; mt < 4; mt++) {
        int rbase = (wm * 2 + (mt >> 1)) * 34 + (mt & 1) * 16 + l15;
#pragma unroll
        for (int dxi = 0; dxi < 3; dxi++) aoff[dxi][mt] = swz_off(rbase + dxi, quad);
    }
#pragma unroll
    for (int nt = 0; nt < 4; nt++) boff[nt] = swz_off(wn * 64 + nt * 16 + l15, quad);

    // stage iteration 'it' (dyi = it>>4, k0 = (it&15)*32) into buffer p
    // wave0 issues 9 vmem ops, waves1-3 issue 8 -> uniform vmcnt(8) is safe
    auto stage_it = [&](int it, int p) {
        int dyi = it >> 4;
        int k0 = (it & 15) << 5;
        size_t ag = (size_t)dyi * dyStride + k0;
        stage16(pA1 + ag, &As[p][wave * 512]);
        stage16(pA2 + ag, &As[p][2048 + wave * 512]);
        if (tid < 32) stage16(pA3 + ag, &As[p][4096]);
        size_t wg = (size_t)(dyi * 3) * (Cc * Cc) + k0;
#pragma unroll
        for (int t = 0; t < 3; t++) {
            size_t tg = wg + (size_t)t * (Cc * Cc);
            stage16(gw1 + tg, &Bs[p][t * 4096 + wave * 1024]);
            stage16(gw2 + tg, &Bs[p][t * 4096 + wave * 1024 + 512]);
        }
    };

    f32x4 acc[4][4] = {};
    stage_it(0, 0);
    for (int it = 0; it < 48; ++it) {
        int p = it & 1;
        if (it + 1 < 48) {
            stage_it(it + 1, p ^ 1);
            asm volatile("s_waitcnt vmcnt(8)" ::: "memory");   // this tile landed; next stays in flight
        } else {
            asm volatile("s_waitcnt vmcnt(0)" ::: "memory");
        }
        __builtin_amdgcn_s_barrier();                          // BAR_A: buf[p] staged
        __builtin_amdgcn_sched_barrier(0);                     // keep reads below BAR_A

        // ---- issue ALL 24 reads, dxi-major (in-order DS returns => counted
        //      lgkm lets MFMA(dxi0) start while dxi1/dxi2 reads are in flight)
        short8 af[3][4], bfv[3][4];
#pragma unroll
        for (int dxi = 0; dxi < 3; dxi++) {
#pragma unroll
            for (int mt = 0; mt < 4; mt++)
                af[dxi][mt] = *(const short8*)&As[p][aoff[dxi][mt]];
#pragma unroll
            for (int nt = 0; nt < 4; nt++)
                bfv[dxi][nt] = *(const short8*)&Bs[p][dxi * 4096 + boff[nt]];
        }

        // ---- MFMA dxi0 + dxi1 (no fences: compiler interleaves with reads)
        __builtin_amdgcn_s_setprio(1);
#pragma unroll
        for (int dxi = 0; dxi < 2; dxi++)
#pragma unroll
            for (int mt = 0; mt < 4; mt++)
#pragma unroll
                for (int nt = 0; nt < 4; nt++)
                    acc[mt][nt] = __builtin_amdgcn_mfma_f32_16x16x32_bf16(af[dxi][mt], bfv[dxi][nt], acc[mt][nt], 0, 0, 0);
        __builtin_amdgcn_s_setprio(0);

        asm volatile("s_waitcnt lgkmcnt(0)" ::: "memory");     // all buf[p] reads done
        __builtin_amdgcn_s_barrier();                          // BAR_B: buf[p] free

        // ---- MFMA dxi2 after the barrier: overlaps other waves' next staging
        __builtin_amdgcn_s_setprio(1);
#pragma unroll
        for (int mt = 0; mt < 4; mt++)
#pragma unroll
            for (int nt = 0; nt < 4; nt++)
                acc[mt][nt] = __builtin_amdgcn_mfma_f32_16x16x32_bf16(af[2][mt], bfv[2][nt], acc[mt][nt], 0, 0, 0);
        __builtin_amdgcn_s_setprio(0);
    }

#pragma unroll
    for (int mt = 0; mt < 4; mt++)
#pragma unroll
        for (int r = 0; r < 4; r++) {
            size_t row = (size_t)(m0 + wm * 64 + mt * 16 + quad * 4 + r) * Cc + n0 + wn * 64 + l15;
#pragma unroll
            for (int nt = 0; nt < 4; nt++) {
                int n = n0 + wn * 64 + nt * 16 + l15;
                out[row + nt * 16] = acc[mt][nt][r] + bias[n] + xres[row + nt * 16];
            }
        }
}

// ---------------------------------------------------------------------------
extern "C" void kernel_launch(void* const* d_in, const int* in_sizes, int n_in,
                              void* d_out, int out_size, void* d_ws, size_t ws_size,
                              hipStream_t stream) {
    const float* x     = (const float*)d_in[0];
    const float* gamma = (const float*)d_in[1];
    const float* beta  = (const float*)d_in[2];
    const float* wq    = (const float*)d_in[3];
    const float* wk    = (const float*)d_in[4];
    const float* wv    = (const float*)d_in[5];
    const float* convw = (const float*)d_in[6];
    const float* convb = (const float*)d_in[7];
    float* out = (float*)d_out;

    // ws layout (time-multiplexed; peak ~71.5 MiB):
    //   [0, 18.9 MiB)  : pad   (written by zero_pad+attention AFTER gemm_qkv)
    //   [0, 4 KiB)     : stats (dead before pad is written)
    //   [4 KiB, +16MiB): xn    (dead before pad is written)
    //   [xn end, +1.5M): wt    (dead before pad is written)
    //   [19 MiB, +32M) : qk    (Q,K rows, stride 1024)
    //   [51 MiB, +16M) : vT    (V transposed [h][d][b*1024+tok])
    //   [67 MiB, +4.5M): wct
    char* ws = (char*)d_ws;
    bf16*  pad   = (bf16*)ws;
    float* stats = (float*)ws;
    bf16*  xn    = (bf16*)(ws + 4096);
    bf16*  wt    = (bf16*)(ws + 4096 + ((size_t)16 << 20));
    bf16*  qk    = (bf16*)(ws + ((size_t)19 << 20));
    bf16*  vt    = (bf16*)(ws + ((size_t)51 << 20));
    bf16*  wct   = (bf16*)(ws + ((size_t)67 << 20));

    // weight prep (dst regions distinct from src-time-live data)
    wtrans3<<<dim3(128, 3), 256, 0, stream>>>(wq, wk, wv, wt);
    wtrans<<<dim3(128, 9), 256, 0, stream>>>(convw, wct);

    gn_stats<<<dim3(Bn * GROUPS), 256, 0, stream>>>(x, stats);
    gn_apply<<<dim3(Mtok * Cc / (4 * 256)), 256, 0, stream>>>(x, stats, gamma, beta, xn);

    gemm_qkv<<<dim3(QKVS / 128, Mtok / 128), 256, 0, stream>>>(xn, wt, qk, vt);

    zero_pad<<<dim3(528), 256, 0, stream>>>(pad);   // after gemm_qkv: region overlaps xn/wt
    attention_mfma<<<dim3(Bn * HEADS * (Ss / 128)), 256, 0, stream>>>(qk, vt, pad);

    conv_mfma<<<dim3(Cc / 128, Mtok / 128), 256, 0, stream>>>(pad, wct, convb, x, out);
}